// Round 12
// baseline (393.960 us; speedup 1.0000x reference)
//
#include <hip/hip_runtime.h>
#include <hip/hip_fp16.h>

#define NN 200000
#define NE 3200000
#define NWG 80          // tail workgroups
#define NBKT 196        // ceil(NN/1024) head workgroups
#define TT 1024
static constexpr float EPSV = 1e-5f;

// ---------------- coherent-point helpers ----------------
__device__ __forceinline__ void stwt(float* p, float v){
  __hip_atomic_store(p, v, __ATOMIC_RELAXED, __HIP_MEMORY_SCOPE_AGENT);
}
__device__ __forceinline__ float ldwt(const float* p){
  return __hip_atomic_load(p, __ATOMIC_RELAXED, __HIP_MEMORY_SCOPE_AGENT);
}
__device__ __forceinline__ void stwt_i(int* p, int v){
  __hip_atomic_store(p, v, __ATOMIC_RELAXED, __HIP_MEMORY_SCOPE_AGENT);
}
__device__ __forceinline__ int ldwt_i(const int* p){
  return __hip_atomic_load(p, __ATOMIC_RELAXED, __HIP_MEMORY_SCOPE_AGENT);
}

// Flag-array barrier, monotonic targets shared across the launch sequence.
// flags at bar[32*wg] (wg in [0,196)); generation at bar[6272].
__device__ __forceinline__ void gridbar(int* bar, int target, int nwg){
  __syncthreads();   // compiler drains each wave's vm/lgkm before s_barrier
  const int t = threadIdx.x;
  if (blockIdx.x == 0){
    if (t >= 1 && t < nwg){
      while (__hip_atomic_load(bar + 32*t, __ATOMIC_RELAXED, __HIP_MEMORY_SCOPE_AGENT) < target)
        __builtin_amdgcn_s_sleep(1);
    }
    __syncthreads();
    if (t == 0)
      __hip_atomic_store(bar + 6272, target, __ATOMIC_RELAXED, __HIP_MEMORY_SCOPE_AGENT);
  } else {
    if (t == 0){
      __atomic_signal_fence(__ATOMIC_SEQ_CST);
      __builtin_amdgcn_s_waitcnt(0);   // this wave's stores durable before arrival flag
      __atomic_signal_fence(__ATOMIC_SEQ_CST);
      __hip_atomic_store(bar + 32*blockIdx.x, target, __ATOMIC_RELAXED, __HIP_MEMORY_SCOPE_AGENT);
      while (__hip_atomic_load(bar + 6272, __ATOMIC_RELAXED, __HIP_MEMORY_SCOPE_AGENT) < target)
        __builtin_amdgcn_s_sleep(2);
    }
    __syncthreads();
  }
}

// ---------------- fused CSR build: count+featprep | wg0 scan | scatter ----------------
// 1024 sub-buckets: key = (dst>>10)<<2 | (src>>16). Within each dst bucket the pairs
// end up src-sorted by 64K window -> agg gathers sweep A/feat in ~2MB L2-resident phases.
__global__ void __launch_bounds__(1024) k_build(const int* __restrict__ ei,
    const float* __restrict__ x, const float* __restrict__ pos,
    float4* __restrict__ feat, float* __restrict__ xstats,
    int* __restrict__ bktCnt, int* __restrict__ bktBase, int* __restrict__ bktCur,
    int* __restrict__ pairs, int* __restrict__ bar){
  __shared__ int cnt[1024]; __shared__ int base[1024]; __shared__ int rank[1024];
  __shared__ float sv[1024], sq[1024];
  const int t = threadIdx.x, wg = blockIdx.x;
  const int tile = wg*16384;
  // phase 0: feat prep + xstats + sub-bucket count (global atomics = coherent)
  cnt[t] = 0;
  int i = wg*1024 + t;
  float xf = 0.f;
  if (i < NN){
    xf = x[i];
    feat[i] = make_float4(xf, pos[3*i], pos[3*i+1], 0.f);
  }
  sv[t] = (i < NN) ? xf : 0.f;
  sq[t] = sv[t]*sv[t];
  __syncthreads();
  #pragma unroll
  for (int k = 0; k < 16; ++k){
    int e = tile + k*1024 + t;
    if (e < NE){
      int d = ei[NE+e], s = ei[e];
      atomicAdd(&cnt[((d>>10)<<2) | (s>>16)], 1);
    }
  }
  for (int o = 512; o > 0; o >>= 1){
    __syncthreads();
    if (t < o){ sv[t]+=sv[t+o]; sq[t]+=sq[t+o]; }
  }
  __syncthreads();
  if (t == 0){ atomicAdd(&xstats[0], sv[0]); atomicAdd(&xstats[1], sq[0]); }
  if (cnt[t]) atomicAdd(&bktCnt[t], cnt[t]);
  gridbar(bar, 1, NBKT);
  // phase 1: wg0 exclusive scan of 1024 global counts (write-through: intra-kernel consumers)
  if (wg == 0){
    int v = ldwt_i(&bktCnt[t]);
    base[t] = v;
    __syncthreads();
    for (int o = 1; o < 1024; o <<= 1){
      int xv = (t >= o) ? base[t-o] : 0;
      __syncthreads();
      base[t] += xv;
      __syncthreads();
    }
    stwt_i(&bktBase[t], base[t]-v); stwt_i(&bktCur[t], base[t]-v);
    if (t == 0) stwt_i(&bktBase[1024], NE);
  }
  gridbar(bar, 2, NBKT);
  // phase 2: scatter (CACHED pairs stores; consumers are later kernels = boundary coherence)
  base[t] = cnt[t] ? atomicAdd(&bktCur[t], cnt[t]) : 0;
  rank[t] = 0;
  __syncthreads();
  #pragma unroll
  for (int k = 0; k < 16; ++k){
    int e = tile + k*1024 + t;
    if (e < NE){
      int d = ei[NE+e], s = ei[e];
      int b = ((d>>10)<<2) | (s>>16);
      int r = atomicAdd(&rank[b], 1);
      pairs[base[b] + r] = (s<<10) | (d & 1023);
    }
  }
}

// ---------------- order-preserving float<->uint for atomicMax ----------------
__device__ __forceinline__ unsigned fenc(float f){
  unsigned u = __float_as_uint(f);
  return (u >> 31) ? ~u : (u | 0x80000000u);
}
__device__ __forceinline__ float fdec(unsigned k){
  unsigned u = (k >> 31) ? (k ^ 0x80000000u) : ~k;
  return __uint_as_float(u);
}
#define ENC_NI 0x007FFFFFu   /* fenc(-inf) */

// ---------------- fused: aggA (LDS-resident H1) + stats + prep2 (fp16 A, no pos bake) ----------------
__global__ void __launch_bounds__(1024) k_b1f(const int* __restrict__ pairs, const int* __restrict__ bktBase,
    const float4* __restrict__ feat, const float* __restrict__ pos,
    const float* __restrict__ w48, const float* __restrict__ biasA,
    const float* __restrict__ w2, float* __restrict__ st1p, uint2* __restrict__ A2,
    int* __restrict__ bar){
  __shared__ unsigned acc[16384];   // 1024 dst x 16 ch (swizzled), 64KB
  const int t = threadIdx.x, wg = blockIdx.x;
  for (int i = t; i < 16384; i += 1024) acc[i] = ENC_NI;
  float wa0[16], wa1[16], wa2[16];
  #pragma unroll
  for (int c = 0; c < 16; ++c){ wa0[c]=w48[c]; wa1[c]=w48[16+c]; wa2[c]=w48[32+c]; }
  const int p0 = bktBase[wg*4], p1 = bktBase[wg*4+4];
  __syncthreads();
  // 4-deep software-pipelined gather loop (MLP: batch loads, then atomic bursts)
  auto edge1 = [&](int pr, float4 f){
    int d = pr & 1023;
    int gb = d << 4, rot = (d >> 1) & 15;
    #pragma unroll
    for (int c = 0; c < 16; ++c){
      float m = f.x*wa0[c] + f.y*wa1[c] + f.z*wa2[c];
      atomicMax(&acc[gb | ((c + rot) & 15)], fenc(m));
    }
  };
  int j = p0 + t;
  for (; j + 3072 < p1; j += 4096){
    int pr0 = pairs[j], pr1 = pairs[j+1024], pr2 = pairs[j+2048], pr3 = pairs[j+3072];
    float4 f0 = feat[pr0>>10], f1 = feat[pr1>>10], f2 = feat[pr2>>10], f3 = feat[pr3>>10];
    edge1(pr0,f0); edge1(pr1,f1); edge1(pr2,f2); edge1(pr3,f3);
  }
  for (; j < p1; j += 1024){ int pr = pairs[j]; edge1(pr, feat[pr>>10]); }
  __syncthreads();
  const int base = wg << 10;
  const int width = min(1024, NN - base);
  // H1 stats only (H1 never leaves LDS)
  {
    const int c = t & 15;
    const float b_c = biasA[c], w1c = w48[16+c], w2c = w48[32+c];
    float ls = 0.f, lq = 0.f;
    for (int i = t; i < width*16; i += 1024){
      int dl = i >> 4, d = base + dl;
      int rot = (dl >> 1) & 15;
      float o = 0.f;
      if (acc[(dl<<4) | rot] != ENC_NI){
        float px = pos[3*d], py = pos[3*d+1];
        o = fdec(acc[(dl<<4) | ((c + rot) & 15)]) + b_c - (px*w1c + py*w2c);
      }
      ls += o; lq += o*o;
    }
    ls += __shfl_xor(ls, 16, 64); ls += __shfl_xor(ls, 32, 64);
    lq += __shfl_xor(lq, 16, 64); lq += __shfl_xor(lq, 32, 64);
    if ((t & 63) < 16){
      int slot = (wg + (t >> 6)) & 15;
      atomicAdd(&st1p[slot*32 + c], ls);
      atomicAdd(&st1p[slot*32 + 16 + c], lq);
    }
  }
  gridbar(bar, 3, NBKT);
  // prep2 from LDS acc -> A2 (fp16, WITHOUT src-pos terms; added exactly in b2f)
  {
    const int lane = t & 63;
    float stv = 0.f;
    if (lane < 32){
      #pragma unroll
      for (int s2 = 0; s2 < 16; ++s2) stv += ldwt(&st1p[s2*32 + lane]);
    }
    const float inv_n = 1.f/(float)NN;
    float mk[16], ik[16];
    #pragma unroll
    for (int k = 0; k < 16; ++k){
      float sm = __shfl(stv, k, 64);
      float sq_ = __shfl(stv, 16 + k, 64);
      float m = sm*inv_n;
      float v = sq_*inv_n - m*m;
      mk[k] = m; ik[k] = rsqrtf(v + EPSV);
    }
    for (int i = t; i < width*4; i += 1024){
      int dl = i >> 2, cg = i & 3, d = base + dl;
      int rot = (dl >> 1) & 15;
      bool valid = (acc[(dl<<4) | rot] != ENC_NI);
      float px = pos[3*d], py = pos[3*d+1];
      float a0=0.f,a1=0.f,a2=0.f,a3=0.f;
      #pragma unroll
      for (int k = 0; k < 16; ++k){
        float o = 0.f;
        if (valid) o = fdec(acc[(dl<<4) | ((k + rot) & 15)]) + biasA[k] - (px*w48[16+k] + py*w48[32+k]);
        float h = fmaxf((o - mk[k])*ik[k], 0.f);
        a0 += h*w2[k*16 + cg*4 + 0];
        a1 += h*w2[k*16 + cg*4 + 1];
        a2 += h*w2[k*16 + cg*4 + 2];
        a3 += h*w2[k*16 + cg*4 + 3];
      }
      __half2 h01 = __floats2half2_rn(a0, a1);
      __half2 h23 = __floats2half2_rn(a2, a3);
      uint2 pk;
      pk.x = *reinterpret_cast<unsigned*>(&h01);
      pk.y = *reinterpret_cast<unsigned*>(&h23);
      A2[d*4 + cg] = pk;
    }
  }
}

// ---------------- fused: aggB (fp16 A gather + exact fp32 src-pos) + stats + comb_pool ----------------
__global__ void __launch_bounds__(1024) k_b2f(const int* __restrict__ pairs, const int* __restrict__ bktBase,
    const uint4* __restrict__ Ah, const float4* __restrict__ feat,
    const float* __restrict__ pos, const float* __restrict__ x,
    const float* __restrict__ wpos, const float* __restrict__ biasB, const float* __restrict__ lw,
    float* __restrict__ st2p, const float* __restrict__ xstats,
    float* __restrict__ mem1, int* __restrict__ bar){
  __shared__ unsigned acc[16384];
  const int t = threadIdx.x, wg = blockIdx.x;
  for (int i = t; i < 16384; i += 1024) acc[i] = ENC_NI;
  float wx[16], wy[16];
  #pragma unroll
  for (int c = 0; c < 16; ++c){ wx[c]=wpos[c]; wy[c]=wpos[16+c]; }
  const int p0 = bktBase[wg*4], p1 = bktBase[wg*4+4];
  __syncthreads();
  auto edge2 = [&](int pr, float4 f, uint4 q0, uint4 q1){
    int d = pr & 1023;
    int gb = d << 4, rot = (d >> 1) & 15;
    float m[16];
    float2 u;
    u = __half22float2(*reinterpret_cast<__half2*>(&q0.x)); m[0]=u.x;  m[1]=u.y;
    u = __half22float2(*reinterpret_cast<__half2*>(&q0.y)); m[2]=u.x;  m[3]=u.y;
    u = __half22float2(*reinterpret_cast<__half2*>(&q0.z)); m[4]=u.x;  m[5]=u.y;
    u = __half22float2(*reinterpret_cast<__half2*>(&q0.w)); m[6]=u.x;  m[7]=u.y;
    u = __half22float2(*reinterpret_cast<__half2*>(&q1.x)); m[8]=u.x;  m[9]=u.y;
    u = __half22float2(*reinterpret_cast<__half2*>(&q1.y)); m[10]=u.x; m[11]=u.y;
    u = __half22float2(*reinterpret_cast<__half2*>(&q1.z)); m[12]=u.x; m[13]=u.y;
    u = __half22float2(*reinterpret_cast<__half2*>(&q1.w)); m[14]=u.x; m[15]=u.y;
    #pragma unroll
    for (int c = 0; c < 16; ++c){
      float mv = m[c] + f.y*wx[c] + f.z*wy[c];
      atomicMax(&acc[gb | ((c + rot) & 15)], fenc(mv));
    }
  };
  int j = p0 + t;
  for (; j + 3072 < p1; j += 4096){
    int pr0 = pairs[j], pr1 = pairs[j+1024], pr2 = pairs[j+2048], pr3 = pairs[j+3072];
    int s0 = pr0>>10, s1 = pr1>>10, s2 = pr2>>10, s3 = pr3>>10;
    float4 f0 = feat[s0], f1 = feat[s1], f2 = feat[s2], f3 = feat[s3];
    uint4 a00 = Ah[s0*2], a01 = Ah[s0*2+1];
    uint4 a10 = Ah[s1*2], a11 = Ah[s1*2+1];
    uint4 a20 = Ah[s2*2], a21 = Ah[s2*2+1];
    uint4 a30 = Ah[s3*2], a31 = Ah[s3*2+1];
    edge2(pr0,f0,a00,a01); edge2(pr1,f1,a10,a11);
    edge2(pr2,f2,a20,a21); edge2(pr3,f3,a30,a31);
  }
  for (; j < p1; j += 1024){
    int pr = pairs[j];
    int s = pr >> 10;
    edge2(pr, feat[s], Ah[s*2], Ah[s*2+1]);
  }
  __syncthreads();
  const int base = wg << 10;
  const int width = min(1024, NN - base);
  const int c = t & 15;
  const float b_c = biasB[c], w1c = wpos[c], w2c = wpos[16+c];
  // H2 stats only (H2 never leaves LDS)
  {
    float ls = 0.f, lq = 0.f;
    for (int i = t; i < width*16; i += 1024){
      int dl = i >> 4, d = base + dl;
      int rot = (dl >> 1) & 15;
      float o = 0.f;
      if (acc[(dl<<4) | rot] != ENC_NI){
        float px = pos[3*d], py = pos[3*d+1];
        o = fdec(acc[(dl<<4) | ((c + rot) & 15)]) + b_c - (px*w1c + py*w2c);
      }
      ls += o; lq += o*o;
    }
    ls += __shfl_xor(ls, 16, 64); ls += __shfl_xor(ls, 32, 64);
    lq += __shfl_xor(lq, 16, 64); lq += __shfl_xor(lq, 32, 64);
    if ((t & 63) < 16){
      int slot = (wg + (t >> 6)) & 15;
      atomicAdd(&st2p[slot*32 + c], ls);
      atomicAdd(&st2p[slot*32 + 16 + c], lq);
    }
  }
  gridbar(bar, 4, NBKT);
  // comb + pool into mem1 (from LDS acc)
  {
    const int lane = t & 63;
    float stv = 0.f;
    if (lane < 32){
      #pragma unroll
      for (int s2 = 0; s2 < 16; ++s2) stv += ldwt(&st2p[s2*32 + lane]);
    }
    const float inv_n = 1.f/(float)NN;
    float sm = __shfl(stv, c, 64), sq_ = __shfl(stv, 16 + c, 64);
    float m2 = sm*inv_n, v2 = sq_*inv_n - m2*m2;
    float i2 = rsqrtf(v2 + EPSV);
    float mx = ldwt(&xstats[0])*inv_n;
    float vx = ldwt(&xstats[1])*inv_n - mx*mx;
    float a = lw[c];
    float sc = a * rsqrtf(a*a*vx + EPSV);
    for (int i = t; i < width*16; i += 1024){
      int dl = i >> 4, d = base + dl;
      int rot = (dl >> 1) & 15;
      float px = pos[3*d], py = pos[3*d+1];
      float o = 0.f;
      if (acc[(dl<<4) | rot] != ENC_NI)
        o = fdec(acc[(dl<<4) | ((c + rot) & 15)]) + b_c - (px*w1c + py*w2c);
      float v = (o - m2)*i2 + (x[d]-mx)*sc;
      v = fmaxf(v, 0.f);
      int cx = (int)(px * 80.f / 240.f); cx = min(max(cx,0),79);
      int cy = (int)(py * 60.f / 180.f); cy = min(max(cy,0),59);
      atomicAdd(&mem1[(cy*80+cx)*16 + c], v);
    }
  }
}

// ---------------- Fused tail: halo-tiled, LDS-resident (unchanged structure) ----------------
struct TailP {
  const float *mem1;
  const float *p1w,*p1b,*p2w,*p2b,*p3w,*p3b;
  const float *c1w2,*c1b2,*c2w2,*c2b2,*lw2,*lb2;
  const float *c1w3,*c1b3,*c2w3,*c2b3,*lw3,*lb3;
  const float *c1w4,*c1b4,*c2w4,*c2b4,*lw4,*lb4;
  float *g2p,*g3p;
  float *stB2sk,*stB2c1,*stB2c2,*stB3sk,*stB3c1,*stB3c2,*stB4sk,*stB4c1,*stB4c2;
  float *out;
  int *bar;
};

template<int GW,int GH,int TW,int TH,int K,int C,bool FIRST>
__device__ __forceinline__ void ph_A(float* buf, float* sv, float* sq,
    const float* __restrict__ Gglob, const float* __restrict__ plw, const float* __restrict__ plb,
    const float* __restrict__ c1w, const float* __restrict__ c1b,
    const float* __restrict__ lw, const float* __restrict__ lb,
    float* stH1, float* stSK, float sx, float sy, int tile)
{
  constexpr int W2=TW+4, nR2=W2*(TH+4);
  constexpr int W1=TW+2, nR1=W1*(TH+2);
  constexpr int nT=TW*TH, NTX=GW/TW;
  const int tx0=(tile%NTX)*TW, ty0=(tile/NTX)*TH;
  float* Gl=buf; float* Sl=Gl+nR2*K; float* H1l=Sl+nR2*C; float* SKl=H1l+nR1*C;
  const int t=threadIdx.x;
  if constexpr (FIRST){
    for (int e=t; e<nR2*K; e+=TT){
      int cell=e/K, k=e-cell*K;
      int gx=tx0-2+cell%W2, gy=ty0-2+cell/W2;
      Sl[e] = (gx>=0&&gx<GW&&gy>=0&&gy<GH) ? Gglob[(gy*GW+gx)*K+k] : 0.f;
    }
    __syncthreads();
    for (int e=t; e<nR2*K; e+=TT){
      int cell=e/K, c=e-cell*K;
      float acc=plb[c];
      #pragma unroll
      for (int k=0;k<K;++k) acc += Sl[cell*K+k]*plw[k*K+c];
      Gl[e] = (acc>1.f)?acc:0.f;
    }
  } else {
    for (int e=t; e<nR2*K; e+=TT){
      int cell=e/K, k=e-cell*K;
      int gx=tx0-2+cell%W2, gy=ty0-2+cell/W2;
      Gl[e] = (gx>=0&&gx<GW&&gy>=0&&gy<GH) ? ldwt(&Gglob[(gy*GW+gx)*K+k]) : 0.f;
    }
  }
  __syncthreads();
  for (int e=t; e<nR2*C; e+=TT){
    int cell=e/C, c=e-cell*C;
    float acc=0.f;
    #pragma unroll 8
    for (int k=0;k<K;++k) acc += Gl[cell*K+k]*c1w[k*C+c];
    Sl[e]=acc;
  }
  float ls=0.f,lq=0.f;
  for (int e=t; e<nT*C; e+=TT){
    int cell=e/C, c=e-cell*C;
    int lx=cell%TW, ly=cell/TW;
    int g2=(ly+2)*W2+(lx+2);
    float acc=lb[c];
    #pragma unroll 8
    for (int k=0;k<K;++k) acc += Gl[g2*K+k]*lw[k*C+c];
    SKl[e]=acc; ls+=acc; lq+=acc*acc;
  }
  __syncthreads();
  sv[t]=ls; sq[t]=lq; __syncthreads();
  for (int o=TT/2;o>=C;o>>=1){ if(t<o){sv[t]+=sv[t+o];sq[t]+=sq[t+o];} __syncthreads(); }
  if (t<C){ atomicAdd(&stSK[t],sv[t]); atomicAdd(&stSK[C+t],sq[t]); }
  __syncthreads();
  ls=0.f; lq=0.f;
  const float NI=-__builtin_inff();
  for (int e=t; e<nR1*C; e+=TT){
    int cell=e/C, c=e-cell*C;
    int lx=cell%W1, ly=cell/W1;
    int gx=tx0-1+lx, gy=ty0-1+ly;
    if (gx<0||gx>=GW||gy<0||gy>=GH) continue;
    float wx=c1w[K*C+c], wy=c1w[(K+1)*C+c];
    float m=NI;
    #pragma unroll
    for (int oy=-1;oy<=1;++oy){
      int ny=gy+oy; if (ny<0||ny>=GH) continue;
      #pragma unroll
      for (int ox=-1;ox<=1;++ox){
        int nx=gx+ox; if (nx<0||nx>=GW) continue;
        int l2=(ly+1+oy)*W2+(lx+1+ox);
        m=fmaxf(m, Sl[l2*C+c]+(ox*sx)*wx+(oy*sy)*wy);
      }
    }
    float val=m+c1b[c];
    H1l[e]=val;
    if (gx>=tx0&&gx<tx0+TW&&gy>=ty0&&gy<ty0+TH){ ls+=val; lq+=val*val; }
  }
  __syncthreads();
  sv[t]=ls; sq[t]=lq; __syncthreads();
  for (int o=TT/2;o>=C;o>>=1){ if(t<o){sv[t]+=sv[t+o];sq[t]+=sq[t+o];} __syncthreads(); }
  if (t<C){ atomicAdd(&stH1[t],sv[t]); atomicAdd(&stH1[C+t],sq[t]); }
}

template<int GW,int GH,int TW,int TH,int K,int C>
__device__ __forceinline__ void ph_B(float* buf, float* sv, float* sq, float* la, float* lbv,
    const float* __restrict__ c2w, const float* __restrict__ c2b,
    const float* stH1, float* stH2, float sx, float sy, int tile)
{
  constexpr int W2=TW+4, nR2=W2*(TH+4);
  constexpr int W1=TW+2, nR1=W1*(TH+2);
  constexpr int nT=TW*TH, NTX=GW/TW;
  const int tx0=(tile%NTX)*TW, ty0=(tile/NTX)*TH;
  float* Gl=buf; float* Sl=Gl+nR2*K; float* H1l=Sl+nR2*C; float* SKl=H1l+nR1*C; float* H2l=SKl+nT*C;
  const int t=threadIdx.x;
  const float invn=1.f/(float)(GW*GH);
  if (t<C){
    float mk=ldwt(&stH1[t])*invn;
    float vk=ldwt(&stH1[C+t])*invn - mk*mk;
    float ik=rsqrtf(vk+EPSV);
    la[t]=ik; lbv[t]=-mk*ik;
  }
  __syncthreads();
  for (int e=t;e<nR1*C;e+=TT){
    int cell=e/C,c=e-cell*C;
    int gx=tx0-1+cell%W1, gy=ty0-1+cell/W1;
    if (gx<0||gx>=GW||gy<0||gy>=GH) continue;
    H1l[e]=fmaxf(H1l[e]*la[c]+lbv[c],0.f);
  }
  __syncthreads();
  for (int e=t;e<nR1*C;e+=TT){
    int cell=e/C,c=e-cell*C;
    int gx=tx0-1+cell%W1, gy=ty0-1+cell/W1;
    if (gx<0||gx>=GW||gy<0||gy>=GH) continue;
    float acc=0.f;
    #pragma unroll 8
    for (int k=0;k<C;++k) acc += H1l[cell*C+k]*c2w[k*C+c];
    Sl[e]=acc;
  }
  __syncthreads();
  float ls=0.f,lq=0.f;
  const float NI=-__builtin_inff();
  for (int e=t;e<nT*C;e+=TT){
    int cell=e/C,c=e-cell*C;
    int lx=cell%TW, ly=cell/TW;
    int gx=tx0+lx, gy=ty0+ly;
    float wx=c2w[C*C+c], wy=c2w[(C+1)*C+c];
    float m=NI;
    #pragma unroll
    for (int oy=-1;oy<=1;++oy){
      int ny=gy+oy; if (ny<0||ny>=GH) continue;
      #pragma unroll
      for (int ox=-1;ox<=1;++ox){
        int nx=gx+ox; if (nx<0||nx>=GW) continue;
        int l1=(ly+1+oy)*W1+(lx+1+ox);
        m=fmaxf(m, Sl[l1*C+c]+(ox*sx)*wx+(oy*sy)*wy);
      }
    }
    float val=m+c2b[c];
    H2l[e]=val; ls+=val; lq+=val*val;
  }
  __syncthreads();
  sv[t]=ls; sq[t]=lq; __syncthreads();
  for (int o=TT/2;o>=C;o>>=1){ if(t<o){sv[t]+=sv[t+o];sq[t]+=sq[t+o];} __syncthreads(); }
  if (t<C){ atomicAdd(&stH2[t],sv[t]); atomicAdd(&stH2[C+t],sq[t]); }
}

template<int GW,int GH,int TW,int TH,int K,int C,bool POOL>
__device__ __forceinline__ void ph_C(float* buf, float* asv, float* asq, float* la, float* lbv,
    const float* stH2, const float* stSK,
    const float* __restrict__ pw, const float* __restrict__ pb,
    float* __restrict__ outg, float* __restrict__ Gpg, int tile)
{
  constexpr int W2=TW+4, nR2=W2*(TH+4);
  constexpr int W1=TW+2, nR1=W1*(TH+2);
  constexpr int nT=TW*TH, NTX=GW/TW;
  const int tx0=(tile%NTX)*TW, ty0=(tile/NTX)*TH;
  float* Gl=buf; float* Sl=Gl+nR2*K; float* H1l=Sl+nR2*C; float* SKl=H1l+nR1*C; float* H2l=SKl+nT*C;
  const int t=threadIdx.x;
  const float invn=1.f/(float)(GW*GH);
  if (t<C){
    float m2=ldwt(&stH2[t])*invn, v2=ldwt(&stH2[C+t])*invn-m2*m2;
    float i2=rsqrtf(v2+EPSV);
    la[t]=i2; lbv[t]=-m2*i2;
    float ms=ldwt(&stSK[t])*invn, vs=ldwt(&stSK[C+t])*invn-ms*ms;
    float is_=rsqrtf(vs+EPSV);
    asv[t]=is_; asq[t]=-ms*is_;
  }
  __syncthreads();
  float* OUTl=Sl;
  for (int e=t;e<nT*C;e+=TT){
    int cell=e/C,c=e-cell*C;
    int lx=cell%TW, ly=cell/TW;
    int gx=tx0+lx, gy=ty0+ly;
    float v=(H2l[e]*la[c]+lbv[c])+(SKl[e]*asv[c]+asq[c]);
    v=fmaxf(v,0.f);
    outg[(gy*GW+gx)*C+c]=v;
    OUTl[e]=v;
  }
  if constexpr (POOL){
    __syncthreads();
    constexpr int PTW=TW/2, PTH=TH/2, nP=PTW*PTH, PGW=GW/2;
    float* Ml=H1l;
    for (int e=t;e<nP*C;e+=TT){
      int pc=e/C,c=e-pc*C;
      int plx=pc%PTW, ply=pc/PTW;
      float s=0.f;
      #pragma unroll
      for (int dy=0;dy<2;++dy)
        #pragma unroll
        for (int dx=0;dx<2;++dx)
          s += OUTl[((2*ply+dy)*TW+(2*plx+dx))*C+c];
      Ml[e]=s;
    }
    __syncthreads();
    for (int e=t;e<nP*C;e+=TT){
      int pc=e/C,c=e-pc*C;
      int plx=pc%PTW, ply=pc/PTW;
      float acc=pb[c];
      #pragma unroll 8
      for (int k=0;k<C;++k) acc += Ml[pc*C+k]*pw[k*C+c];
      int gpx=tx0/2+plx, gpy=ty0/2+ply;
      stwt(&Gpg[(gpy*PGW+gpx)*C+c], (acc>1.f)?acc:0.f);
    }
  }
  (void)nR1;
}

__global__ void __launch_bounds__(TT) k_tail(TailP P){
  __shared__ float sv[TT], sq[TT], la[128], lbv[128];
  __shared__ float buf[13824];
  int* bar = P.bar;
  const int tile = blockIdx.x;

  if (tile < 80) ph_A<80,60,10,6,16,32,true >(buf,sv,sq,P.mem1,P.p1w,P.p1b,P.c1w2,P.c1b2,P.lw2,P.lb2,P.stB2c1,P.stB2sk,3.f,3.f,tile);
  gridbar(bar, 5, NWG);
  if (tile < 80) ph_B<80,60,10,6,16,32>(buf,sv,sq,la,lbv,P.c2w2,P.c2b2,P.stB2c1,P.stB2c2,3.f,3.f,tile);
  gridbar(bar, 6, NWG);
  if (tile < 80) ph_C<80,60,10,6,16,32,true >(buf,sv,sq,la,lbv,P.stB2c2,P.stB2sk,P.p2w,P.p2b,P.out,P.g2p,tile);
  gridbar(bar, 7, NWG);
  if (tile < 50) ph_A<40,30,4,6,32,64,false>(buf,sv,sq,P.g2p,nullptr,nullptr,P.c1w3,P.c1b3,P.lw3,P.lb3,P.stB3c1,P.stB3sk,6.f,6.f,tile);
  gridbar(bar, 8, NWG);
  if (tile < 50) ph_B<40,30,4,6,32,64>(buf,sv,sq,la,lbv,P.c2w3,P.c2b3,P.stB3c1,P.stB3c2,6.f,6.f,tile);
  gridbar(bar, 9, NWG);
  if (tile < 50) ph_C<40,30,4,6,32,64,true >(buf,sv,sq,la,lbv,P.stB3c2,P.stB3sk,P.p3w,P.p3b,P.out+153600,P.g3p,tile);
  gridbar(bar, 10, NWG);
  if (tile < 50) ph_A<20,15,2,3,64,128,false>(buf,sv,sq,P.g3p,nullptr,nullptr,P.c1w4,P.c1b4,P.lw4,P.lb4,P.stB4c1,P.stB4sk,12.f,12.f,tile);
  gridbar(bar, 11, NWG);
  if (tile < 50) ph_B<20,15,2,3,64,128>(buf,sv,sq,la,lbv,P.c2w4,P.c2b4,P.stB4c1,P.stB4c2,12.f,12.f,tile);
  gridbar(bar, 12, NWG);
  if (tile < 50) ph_C<20,15,2,3,64,128,false>(buf,sv,sq,la,lbv,P.stB4c2,P.stB4sk,nullptr,nullptr,P.out+230400,nullptr,tile);
}

extern "C" void kernel_launch(void* const* d_in, const int* in_sizes, int n_in,
                              void* d_out, int out_size, void* d_ws, size_t ws_size,
                              hipStream_t stream){
  const float* x   = (const float*)d_in[0];
  const float* pos = (const float*)d_in[1];
  const int*   ei  = (const int*)d_in[2];
  const float* b1_c1w = (const float*)d_in[3];
  const float* b1_c1b = (const float*)d_in[4];
  const float* b1_c2w = (const float*)d_in[5];
  const float* b1_c2b = (const float*)d_in[6];
  const float* b1_lw  = (const float*)d_in[7];
  const float* b2_c1w = (const float*)d_in[9];
  const float* b2_c1b = (const float*)d_in[10];
  const float* b2_c2w = (const float*)d_in[11];
  const float* b2_c2b = (const float*)d_in[12];
  const float* b2_lw  = (const float*)d_in[13];
  const float* b2_lb  = (const float*)d_in[14];
  const float* b3_c1w = (const float*)d_in[15];
  const float* b3_c1b = (const float*)d_in[16];
  const float* b3_c2w = (const float*)d_in[17];
  const float* b3_c2b = (const float*)d_in[18];
  const float* b3_lw  = (const float*)d_in[19];
  const float* b3_lb  = (const float*)d_in[20];
  const float* b4_c1w = (const float*)d_in[21];
  const float* b4_c1b = (const float*)d_in[22];
  const float* b4_c2w = (const float*)d_in[23];
  const float* b4_c2b = (const float*)d_in[24];
  const float* b4_lw  = (const float*)d_in[25];
  const float* b4_lb  = (const float*)d_in[26];
  const float* p1w = (const float*)d_in[27];
  const float* p1b = (const float*)d_in[28];
  const float* p2w = (const float*)d_in[29];
  const float* p2b = (const float*)d_in[30];
  const float* p3w = (const float*)d_in[31];
  const float* p3b = (const float*)d_in[32];
  float* out = (float*)d_out;

  // ---- workspace carve (fp16 A in first half of A region) ----
  float4* feat = (float4*)d_ws;        // NN float4
  float* A  = (float*)(feat + NN);     // NN*16 fp32 region reserved; fp16 A uses NN*8 uints
  float* g2p  = A;                     // 1200*32 — alias, A dead after k_b2f
  float* g3p  = A + 38400;             // 300*64
  // Z region (single memset): sub-bucket counters, barrier flags, stats, mem1
  int* bktCnt  = (int*)(A + NN*16);    // 1024
  int* bktBase = bktCnt + 1024;        // 1025, pad to 1056
  int* bktCur  = bktCnt + 2080;        // 1024; ends 3104, pad to 3200
  int* bar     = bktCnt + 3200;        // flags 196 x stride-32, gen at [6272]; pad to 6400
  float* STz   = (float*)(bktCnt + 3200 + 6400);
  float* xstats = STz;                 // 2
  float* st1p   = STz + 64;            // 16 slots x 32
  float* st2p   = STz + 576;           // 16 slots x 32
  float* stB2sk = STz + 1088;          // 64
  float* stB2c1 = STz + 1152;          // 64
  float* stB2c2 = STz + 1216;          // 64
  float* stB3sk = STz + 1280;          // 128
  float* stB3c1 = STz + 1408;          // 128
  float* stB3c2 = STz + 1536;          // 128
  float* stB4sk = STz + 1664;          // 256
  float* stB4c1 = STz + 1920;          // 256
  float* stB4c2 = STz + 2176;          // ..2431, pad to 2560
  float* mem1   = STz + 2560;          // 76800
  const size_t ZBYTES = (size_t)(3200 + 6400 + 2560 + 76800) * 4;
  int* pairs  = (int*)(mem1 + 76800);  // NE ints

  hipMemsetAsync(bktCnt, 0, ZBYTES, stream);

  // 4 launches + memset
  k_build<<<NBKT, TT, 0, stream>>>(ei, x, pos, feat, xstats, bktCnt, bktBase, bktCur, pairs, bar);
  k_b1f  <<<NBKT, TT, 0, stream>>>(pairs, bktBase, feat, pos,
                                   b1_c1w, b1_c1b, b1_c2w, st1p, (uint2*)A, bar);
  k_b2f  <<<NBKT, TT, 0, stream>>>(pairs, bktBase, (const uint4*)A, feat, pos, x,
                                   b1_c2w+256, b1_c2b, b1_lw, st2p, xstats, mem1, bar);

  TailP P;
  P.mem1 = mem1;
  P.p1w = p1w; P.p1b = p1b; P.p2w = p2w; P.p2b = p2b; P.p3w = p3w; P.p3b = p3b;
  P.c1w2 = b2_c1w; P.c1b2 = b2_c1b; P.c2w2 = b2_c2w; P.c2b2 = b2_c2b; P.lw2 = b2_lw; P.lb2 = b2_lb;
  P.c1w3 = b3_c1w; P.c1b3 = b3_c1b; P.c2w3 = b3_c2w; P.c2b3 = b3_c2b; P.lw3 = b3_lw; P.lb3 = b3_lb;
  P.c1w4 = b4_c1w; P.c1b4 = b4_c1b; P.c2w4 = b4_c2w; P.c2b4 = b4_c2b; P.lw4 = b4_lw; P.lb4 = b4_lb;
  P.g2p = g2p; P.g3p = g3p;
  P.stB2sk = stB2sk; P.stB2c1 = stB2c1; P.stB2c2 = stB2c2;
  P.stB3sk = stB3sk; P.stB3c1 = stB3c1; P.stB3c2 = stB3c2;
  P.stB4sk = stB4sk; P.stB4c1 = stB4c1; P.stB4c2 = stB4c2;
  P.out = out; P.bar = bar;
  k_tail<<<NWG, TT, 0, stream>>>(P);
}

// Round 13
// 386.444 us; speedup vs baseline: 1.0195x; 1.0195x over previous
//
#include <hip/hip_runtime.h>
#include <hip/hip_fp16.h>

#define NN 200000
#define NE 3200000
#define NWG 200         // tail workgroups (= block-2 tile count)
#define NBKT 196        // ceil(NN/1024) head workgroups
#define TT 1024
static constexpr float EPSV = 1e-5f;

// ---------------- coherent-point helpers ----------------
__device__ __forceinline__ void stwt(float* p, float v){
  __hip_atomic_store(p, v, __ATOMIC_RELAXED, __HIP_MEMORY_SCOPE_AGENT);
}
__device__ __forceinline__ float ldwt(const float* p){
  return __hip_atomic_load(p, __ATOMIC_RELAXED, __HIP_MEMORY_SCOPE_AGENT);
}
__device__ __forceinline__ void stwt_i(int* p, int v){
  __hip_atomic_store(p, v, __ATOMIC_RELAXED, __HIP_MEMORY_SCOPE_AGENT);
}
__device__ __forceinline__ int ldwt_i(const int* p){
  return __hip_atomic_load(p, __ATOMIC_RELAXED, __HIP_MEMORY_SCOPE_AGENT);
}

// Flag-array barrier, monotonic targets shared across the launch sequence.
// flags at bar[32*wg] (wg in [0,200)); generation at bar[6400].
__device__ __forceinline__ void gridbar(int* bar, int target, int nwg){
  __syncthreads();   // compiler drains each wave's vm/lgkm before s_barrier
  const int t = threadIdx.x;
  if (blockIdx.x == 0){
    if (t >= 1 && t < nwg){
      while (__hip_atomic_load(bar + 32*t, __ATOMIC_RELAXED, __HIP_MEMORY_SCOPE_AGENT) < target)
        __builtin_amdgcn_s_sleep(1);
    }
    __syncthreads();
    if (t == 0)
      __hip_atomic_store(bar + 6400, target, __ATOMIC_RELAXED, __HIP_MEMORY_SCOPE_AGENT);
  } else {
    if (t == 0){
      __atomic_signal_fence(__ATOMIC_SEQ_CST);
      __builtin_amdgcn_s_waitcnt(0);   // this wave's stores durable before arrival flag
      __atomic_signal_fence(__ATOMIC_SEQ_CST);
      __hip_atomic_store(bar + 32*blockIdx.x, target, __ATOMIC_RELAXED, __HIP_MEMORY_SCOPE_AGENT);
      while (__hip_atomic_load(bar + 6400, __ATOMIC_RELAXED, __HIP_MEMORY_SCOPE_AGENT) < target)
        __builtin_amdgcn_s_sleep(2);
    }
    __syncthreads();
  }
}

// ---------------- fused CSR build: count+featprep | wg0 scan | scatter ----------------
// 1024 sub-buckets: key = (dst>>10)<<2 | (src>>16). Within each dst bucket the pairs
// end up src-sorted by 64K window -> agg gathers sweep A/feat in ~2MB L2-resident phases.
__global__ void __launch_bounds__(1024) k_build(const int* __restrict__ ei,
    const float* __restrict__ x, const float* __restrict__ pos,
    float4* __restrict__ feat, float* __restrict__ xstats,
    int* __restrict__ bktCnt, int* __restrict__ bktBase, int* __restrict__ bktCur,
    int* __restrict__ pairs, int* __restrict__ bar){
  __shared__ int cnt[1024]; __shared__ int base[1024]; __shared__ int rank[1024];
  __shared__ float sv[1024], sq[1024];
  const int t = threadIdx.x, wg = blockIdx.x;
  const int tile = wg*16384;
  // phase 0: feat prep + xstats + sub-bucket count (global atomics = coherent)
  cnt[t] = 0;
  int i = wg*1024 + t;
  float xf = 0.f;
  if (i < NN){
    xf = x[i];
    feat[i] = make_float4(xf, pos[3*i], pos[3*i+1], 0.f);
  }
  sv[t] = (i < NN) ? xf : 0.f;
  sq[t] = sv[t]*sv[t];
  __syncthreads();
  #pragma unroll
  for (int k = 0; k < 16; ++k){
    int e = tile + k*1024 + t;
    if (e < NE){
      int d = ei[NE+e], s = ei[e];
      atomicAdd(&cnt[((d>>10)<<2) | (s>>16)], 1);
    }
  }
  for (int o = 512; o > 0; o >>= 1){
    __syncthreads();
    if (t < o){ sv[t]+=sv[t+o]; sq[t]+=sq[t+o]; }
  }
  __syncthreads();
  if (t == 0){ atomicAdd(&xstats[0], sv[0]); atomicAdd(&xstats[1], sq[0]); }
  if (cnt[t]) atomicAdd(&bktCnt[t], cnt[t]);
  gridbar(bar, 1, NBKT);
  // phase 1: wg0 exclusive scan of 1024 global counts (write-through: intra-kernel consumers)
  if (wg == 0){
    int v = ldwt_i(&bktCnt[t]);
    base[t] = v;
    __syncthreads();
    for (int o = 1; o < 1024; o <<= 1){
      int xv = (t >= o) ? base[t-o] : 0;
      __syncthreads();
      base[t] += xv;
      __syncthreads();
    }
    stwt_i(&bktBase[t], base[t]-v); stwt_i(&bktCur[t], base[t]-v);
    if (t == 0) stwt_i(&bktBase[1024], NE);
  }
  gridbar(bar, 2, NBKT);
  // phase 2: scatter (CACHED pairs stores; consumers are later kernels = boundary coherence)
  base[t] = cnt[t] ? atomicAdd(&bktCur[t], cnt[t]) : 0;
  rank[t] = 0;
  __syncthreads();
  #pragma unroll
  for (int k = 0; k < 16; ++k){
    int e = tile + k*1024 + t;
    if (e < NE){
      int d = ei[NE+e], s = ei[e];
      int b = ((d>>10)<<2) | (s>>16);
      int r = atomicAdd(&rank[b], 1);
      pairs[base[b] + r] = (s<<10) | (d & 1023);
    }
  }
}

// ---------------- order-preserving float<->uint for atomicMax ----------------
__device__ __forceinline__ unsigned fenc(float f){
  unsigned u = __float_as_uint(f);
  return (u >> 31) ? ~u : (u | 0x80000000u);
}
__device__ __forceinline__ float fdec(unsigned k){
  unsigned u = (k >> 31) ? (k ^ 0x80000000u) : ~k;
  return __uint_as_float(u);
}
#define ENC_NI 0x007FFFFFu   /* fenc(-inf) */

// ---------------- fused: aggA (LDS-resident H1) + stats + prep2 (fp16 A, no pos bake) ----------------
__global__ void __launch_bounds__(1024) k_b1f(const int* __restrict__ pairs, const int* __restrict__ bktBase,
    const float4* __restrict__ feat, const float* __restrict__ pos,
    const float* __restrict__ w48, const float* __restrict__ biasA,
    const float* __restrict__ w2, float* __restrict__ st1p, uint2* __restrict__ A2,
    int* __restrict__ bar){
  __shared__ unsigned acc[16384];   // 1024 dst x 16 ch (swizzled), 64KB
  const int t = threadIdx.x, wg = blockIdx.x;
  for (int i = t; i < 16384; i += 1024) acc[i] = ENC_NI;
  float wa0[16], wa1[16], wa2[16];
  #pragma unroll
  for (int c = 0; c < 16; ++c){ wa0[c]=w48[c]; wa1[c]=w48[16+c]; wa2[c]=w48[32+c]; }
  const int p0 = bktBase[wg*4], p1 = bktBase[wg*4+4];
  __syncthreads();
  for (int j = p0 + t; j < p1; j += 1024){
    int pr = pairs[j];
    float4 f = feat[pr >> 10];
    int d = pr & 1023;
    int gb = d << 4, rot = (d >> 1) & 15;
    #pragma unroll
    for (int c = 0; c < 16; ++c){
      float m = f.x*wa0[c] + f.y*wa1[c] + f.z*wa2[c];
      atomicMax(&acc[gb | ((c + rot) & 15)], fenc(m));
    }
  }
  __syncthreads();
  const int base = wg << 10;
  const int width = min(1024, NN - base);
  // H1 stats only (H1 never leaves LDS)
  {
    const int c = t & 15;
    const float b_c = biasA[c], w1c = w48[16+c], w2c = w48[32+c];
    float ls = 0.f, lq = 0.f;
    for (int i = t; i < width*16; i += 1024){
      int dl = i >> 4, d = base + dl;
      int rot = (dl >> 1) & 15;
      float o = 0.f;
      if (acc[(dl<<4) | rot] != ENC_NI){
        float px = pos[3*d], py = pos[3*d+1];
        o = fdec(acc[(dl<<4) | ((c + rot) & 15)]) + b_c - (px*w1c + py*w2c);
      }
      ls += o; lq += o*o;
    }
    ls += __shfl_xor(ls, 16, 64); ls += __shfl_xor(ls, 32, 64);
    lq += __shfl_xor(lq, 16, 64); lq += __shfl_xor(lq, 32, 64);
    if ((t & 63) < 16){
      int slot = (wg + (t >> 6)) & 15;
      atomicAdd(&st1p[slot*32 + c], ls);
      atomicAdd(&st1p[slot*32 + 16 + c], lq);
    }
  }
  gridbar(bar, 3, NBKT);
  // prep2 from LDS acc -> A2 (fp16, WITHOUT src-pos terms; added exactly in b2f)
  {
    const int lane = t & 63;
    float stv = 0.f;
    if (lane < 32){
      #pragma unroll
      for (int s2 = 0; s2 < 16; ++s2) stv += ldwt(&st1p[s2*32 + lane]);
    }
    const float inv_n = 1.f/(float)NN;
    float mk[16], ik[16];
    #pragma unroll
    for (int k = 0; k < 16; ++k){
      float sm = __shfl(stv, k, 64);
      float sq_ = __shfl(stv, 16 + k, 64);
      float m = sm*inv_n;
      float v = sq_*inv_n - m*m;
      mk[k] = m; ik[k] = rsqrtf(v + EPSV);
    }
    for (int i = t; i < width*4; i += 1024){
      int dl = i >> 2, cg = i & 3, d = base + dl;
      int rot = (dl >> 1) & 15;
      bool valid = (acc[(dl<<4) | rot] != ENC_NI);
      float px = pos[3*d], py = pos[3*d+1];
      float a0=0.f,a1=0.f,a2=0.f,a3=0.f;
      #pragma unroll
      for (int k = 0; k < 16; ++k){
        float o = 0.f;
        if (valid) o = fdec(acc[(dl<<4) | ((k + rot) & 15)]) + biasA[k] - (px*w48[16+k] + py*w48[32+k]);
        float h = fmaxf((o - mk[k])*ik[k], 0.f);
        a0 += h*w2[k*16 + cg*4 + 0];
        a1 += h*w2[k*16 + cg*4 + 1];
        a2 += h*w2[k*16 + cg*4 + 2];
        a3 += h*w2[k*16 + cg*4 + 3];
      }
      __half2 h01 = __floats2half2_rn(a0, a1);
      __half2 h23 = __floats2half2_rn(a2, a3);
      uint2 pk;
      pk.x = *reinterpret_cast<unsigned*>(&h01);
      pk.y = *reinterpret_cast<unsigned*>(&h23);
      A2[d*4 + cg] = pk;
    }
  }
}

// ---------------- fused: aggB (fp16 A gather + exact fp32 src-pos) + stats + comb_pool ----------------
__global__ void __launch_bounds__(1024) k_b2f(const int* __restrict__ pairs, const int* __restrict__ bktBase,
    const uint4* __restrict__ Ah, const float4* __restrict__ feat,
    const float* __restrict__ pos, const float* __restrict__ x,
    const float* __restrict__ wpos, const float* __restrict__ biasB, const float* __restrict__ lw,
    float* __restrict__ st2p, const float* __restrict__ xstats,
    float* __restrict__ mem1, int* __restrict__ bar){
  __shared__ unsigned acc[16384];
  const int t = threadIdx.x, wg = blockIdx.x;
  for (int i = t; i < 16384; i += 1024) acc[i] = ENC_NI;
  float wx[16], wy[16];
  #pragma unroll
  for (int c = 0; c < 16; ++c){ wx[c]=wpos[c]; wy[c]=wpos[16+c]; }
  const int p0 = bktBase[wg*4], p1 = bktBase[wg*4+4];
  __syncthreads();
  for (int j = p0 + t; j < p1; j += 1024){
    int pr = pairs[j];
    int s = pr >> 10, d = pr & 1023;
    int gb = d << 4, rot = (d >> 1) & 15;
    float4 f = feat[s];             // src-window-ordered -> L2-resident phase
    uint4 q0 = Ah[s*2+0], q1 = Ah[s*2+1];   // 32B fp16 A row, same ordering
    float m[16];
    {
      float2 u;
      u = __half22float2(*reinterpret_cast<__half2*>(&q0.x)); m[0]=u.x;  m[1]=u.y;
      u = __half22float2(*reinterpret_cast<__half2*>(&q0.y)); m[2]=u.x;  m[3]=u.y;
      u = __half22float2(*reinterpret_cast<__half2*>(&q0.z)); m[4]=u.x;  m[5]=u.y;
      u = __half22float2(*reinterpret_cast<__half2*>(&q0.w)); m[6]=u.x;  m[7]=u.y;
      u = __half22float2(*reinterpret_cast<__half2*>(&q1.x)); m[8]=u.x;  m[9]=u.y;
      u = __half22float2(*reinterpret_cast<__half2*>(&q1.y)); m[10]=u.x; m[11]=u.y;
      u = __half22float2(*reinterpret_cast<__half2*>(&q1.z)); m[12]=u.x; m[13]=u.y;
      u = __half22float2(*reinterpret_cast<__half2*>(&q1.w)); m[14]=u.x; m[15]=u.y;
    }
    #pragma unroll
    for (int c = 0; c < 16; ++c){
      float mv = m[c] + f.y*wx[c] + f.z*wy[c];
      atomicMax(&acc[gb | ((c + rot) & 15)], fenc(mv));
    }
  }
  __syncthreads();
  const int base = wg << 10;
  const int width = min(1024, NN - base);
  const int c = t & 15;
  const float b_c = biasB[c], w1c = wpos[c], w2c = wpos[16+c];
  // H2 stats only (H2 never leaves LDS)
  {
    float ls = 0.f, lq = 0.f;
    for (int i = t; i < width*16; i += 1024){
      int dl = i >> 4, d = base + dl;
      int rot = (dl >> 1) & 15;
      float o = 0.f;
      if (acc[(dl<<4) | rot] != ENC_NI){
        float px = pos[3*d], py = pos[3*d+1];
        o = fdec(acc[(dl<<4) | ((c + rot) & 15)]) + b_c - (px*w1c + py*w2c);
      }
      ls += o; lq += o*o;
    }
    ls += __shfl_xor(ls, 16, 64); ls += __shfl_xor(ls, 32, 64);
    lq += __shfl_xor(lq, 16, 64); lq += __shfl_xor(lq, 32, 64);
    if ((t & 63) < 16){
      int slot = (wg + (t >> 6)) & 15;
      atomicAdd(&st2p[slot*32 + c], ls);
      atomicAdd(&st2p[slot*32 + 16 + c], lq);
    }
  }
  gridbar(bar, 4, NBKT);
  // comb + pool into mem1 (from LDS acc)
  {
    const int lane = t & 63;
    float stv = 0.f;
    if (lane < 32){
      #pragma unroll
      for (int s2 = 0; s2 < 16; ++s2) stv += ldwt(&st2p[s2*32 + lane]);
    }
    const float inv_n = 1.f/(float)NN;
    float sm = __shfl(stv, c, 64), sq_ = __shfl(stv, 16 + c, 64);
    float m2 = sm*inv_n, v2 = sq_*inv_n - m2*m2;
    float i2 = rsqrtf(v2 + EPSV);
    float mx = ldwt(&xstats[0])*inv_n;
    float vx = ldwt(&xstats[1])*inv_n - mx*mx;
    float a = lw[c];
    float sc = a * rsqrtf(a*a*vx + EPSV);
    for (int i = t; i < width*16; i += 1024){
      int dl = i >> 4, d = base + dl;
      int rot = (dl >> 1) & 15;
      float px = pos[3*d], py = pos[3*d+1];
      float o = 0.f;
      if (acc[(dl<<4) | rot] != ENC_NI)
        o = fdec(acc[(dl<<4) | ((c + rot) & 15)]) + b_c - (px*w1c + py*w2c);
      float v = (o - m2)*i2 + (x[d]-mx)*sc;
      v = fmaxf(v, 0.f);
      int cx = (int)(px * 80.f / 240.f); cx = min(max(cx,0),79);
      int cy = (int)(py * 60.f / 180.f); cy = min(max(cy,0),59);
      atomicAdd(&mem1[(cy*80+cx)*16 + c], v);
    }
  }
}

// ---------------- Fused tail: halo-tiled, LDS-resident, finer tiles (200/100/50 WGs) ----------------
struct TailP {
  const float *mem1;
  const float *p1w,*p1b,*p2w,*p2b,*p3w,*p3b;
  const float *c1w2,*c1b2,*c2w2,*c2b2,*lw2,*lb2;
  const float *c1w3,*c1b3,*c2w3,*c2b3,*lw3,*lb3;
  const float *c1w4,*c1b4,*c2w4,*c2b4,*lw4,*lb4;
  float *g2p,*g3p;
  float *stB2sk,*stB2c1,*stB2c2,*stB3sk,*stB3c1,*stB3c2,*stB4sk,*stB4c1,*stB4c2;
  float *out;
  int *bar;
};

template<int GW,int GH,int TW,int TH,int K,int C,bool FIRST>
__device__ __forceinline__ void ph_A(float* buf, float* sv, float* sq,
    const float* __restrict__ Gglob, const float* __restrict__ plw, const float* __restrict__ plb,
    const float* __restrict__ c1w, const float* __restrict__ c1b,
    const float* __restrict__ lw, const float* __restrict__ lb,
    float* stH1, float* stSK, float sx, float sy, int tile)
{
  constexpr int W2=TW+4, nR2=W2*(TH+4);
  constexpr int W1=TW+2, nR1=W1*(TH+2);
  constexpr int nT=TW*TH, NTX=GW/TW;
  const int tx0=(tile%NTX)*TW, ty0=(tile/NTX)*TH;
  float* Gl=buf; float* Sl=Gl+nR2*K; float* H1l=Sl+nR2*C; float* SKl=H1l+nR1*C;
  const int t=threadIdx.x;
  if constexpr (FIRST){
    for (int e=t; e<nR2*K; e+=TT){
      int cell=e/K, k=e-cell*K;
      int gx=tx0-2+cell%W2, gy=ty0-2+cell/W2;
      Sl[e] = (gx>=0&&gx<GW&&gy>=0&&gy<GH) ? Gglob[(gy*GW+gx)*K+k] : 0.f;
    }
    __syncthreads();
    for (int e=t; e<nR2*K; e+=TT){
      int cell=e/K, c=e-cell*K;
      float acc=plb[c];
      #pragma unroll
      for (int k=0;k<K;++k) acc += Sl[cell*K+k]*plw[k*K+c];
      Gl[e] = (acc>1.f)?acc:0.f;
    }
  } else {
    for (int e=t; e<nR2*K; e+=TT){
      int cell=e/K, k=e-cell*K;
      int gx=tx0-2+cell%W2, gy=ty0-2+cell/W2;
      Gl[e] = (gx>=0&&gx<GW&&gy>=0&&gy<GH) ? ldwt(&Gglob[(gy*GW+gx)*K+k]) : 0.f;
    }
  }
  __syncthreads();
  for (int e=t; e<nR2*C; e+=TT){
    int cell=e/C, c=e-cell*C;
    float acc=0.f;
    #pragma unroll 8
    for (int k=0;k<K;++k) acc += Gl[cell*K+k]*c1w[k*C+c];
    Sl[e]=acc;
  }
  float ls=0.f,lq=0.f;
  for (int e=t; e<nT*C; e+=TT){
    int cell=e/C, c=e-cell*C;
    int lx=cell%TW, ly=cell/TW;
    int g2=(ly+2)*W2+(lx+2);
    float acc=lb[c];
    #pragma unroll 8
    for (int k=0;k<K;++k) acc += Gl[g2*K+k]*lw[k*C+c];
    SKl[e]=acc; ls+=acc; lq+=acc*acc;
  }
  __syncthreads();
  sv[t]=ls; sq[t]=lq; __syncthreads();
  for (int o=TT/2;o>=C;o>>=1){ if(t<o){sv[t]+=sv[t+o];sq[t]+=sq[t+o];} __syncthreads(); }
  if (t<C){ atomicAdd(&stSK[t],sv[t]); atomicAdd(&stSK[C+t],sq[t]); }
  __syncthreads();
  ls=0.f; lq=0.f;
  const float NI=-__builtin_inff();
  for (int e=t; e<nR1*C; e+=TT){
    int cell=e/C, c=e-cell*C;
    int lx=cell%W1, ly=cell/W1;
    int gx=tx0-1+lx, gy=ty0-1+ly;
    if (gx<0||gx>=GW||gy<0||gy>=GH) continue;
    float wx=c1w[K*C+c], wy=c1w[(K+1)*C+c];
    float m=NI;
    #pragma unroll
    for (int oy=-1;oy<=1;++oy){
      int ny=gy+oy; if (ny<0||ny>=GH) continue;
      #pragma unroll
      for (int ox=-1;ox<=1;++ox){
        int nx=gx+ox; if (nx<0||nx>=GW) continue;
        int l2=(ly+1+oy)*W2+(lx+1+ox);
        m=fmaxf(m, Sl[l2*C+c]+(ox*sx)*wx+(oy*sy)*wy);
      }
    }
    float val=m+c1b[c];
    H1l[e]=val;
    if (gx>=tx0&&gx<tx0+TW&&gy>=ty0&&gy<ty0+TH){ ls+=val; lq+=val*val; }
  }
  __syncthreads();
  sv[t]=ls; sq[t]=lq; __syncthreads();
  for (int o=TT/2;o>=C;o>>=1){ if(t<o){sv[t]+=sv[t+o];sq[t]+=sq[t+o];} __syncthreads(); }
  if (t<C){ atomicAdd(&stH1[t],sv[t]); atomicAdd(&stH1[C+t],sq[t]); }
}

template<int GW,int GH,int TW,int TH,int K,int C>
__device__ __forceinline__ void ph_B(float* buf, float* sv, float* sq, float* la, float* lbv,
    const float* __restrict__ c2w, const float* __restrict__ c2b,
    const float* stH1, float* stH2, float sx, float sy, int tile)
{
  constexpr int W2=TW+4, nR2=W2*(TH+4);
  constexpr int W1=TW+2, nR1=W1*(TH+2);
  constexpr int nT=TW*TH, NTX=GW/TW;
  const int tx0=(tile%NTX)*TW, ty0=(tile/NTX)*TH;
  float* Gl=buf; float* Sl=Gl+nR2*K; float* H1l=Sl+nR2*C; float* SKl=H1l+nR1*C; float* H2l=SKl+nT*C;
  const int t=threadIdx.x;
  const float invn=1.f/(float)(GW*GH);
  if (t<C){
    float mk=ldwt(&stH1[t])*invn;
    float vk=ldwt(&stH1[C+t])*invn - mk*mk;
    float ik=rsqrtf(vk+EPSV);
    la[t]=ik; lbv[t]=-mk*ik;
  }
  __syncthreads();
  for (int e=t;e<nR1*C;e+=TT){
    int cell=e/C,c=e-cell*C;
    int gx=tx0-1+cell%W1, gy=ty0-1+cell/W1;
    if (gx<0||gx>=GW||gy<0||gy>=GH) continue;
    H1l[e]=fmaxf(H1l[e]*la[c]+lbv[c],0.f);
  }
  __syncthreads();
  for (int e=t;e<nR1*C;e+=TT){
    int cell=e/C,c=e-cell*C;
    int gx=tx0-1+cell%W1, gy=ty0-1+cell/W1;
    if (gx<0||gx>=GW||gy<0||gy>=GH) continue;
    float acc=0.f;
    #pragma unroll 8
    for (int k=0;k<C;++k) acc += H1l[cell*C+k]*c2w[k*C+c];
    Sl[e]=acc;
  }
  __syncthreads();
  float ls=0.f,lq=0.f;
  const float NI=-__builtin_inff();
  for (int e=t;e<nT*C;e+=TT){
    int cell=e/C,c=e-cell*C;
    int lx=cell%TW, ly=cell/TW;
    int gx=tx0+lx, gy=ty0+ly;
    float wx=c2w[C*C+c], wy=c2w[(C+1)*C+c];
    float m=NI;
    #pragma unroll
    for (int oy=-1;oy<=1;++oy){
      int ny=gy+oy; if (ny<0||ny>=GH) continue;
      #pragma unroll
      for (int ox=-1;ox<=1;++ox){
        int nx=gx+ox; if (nx<0||nx>=GW) continue;
        int l1=(ly+1+oy)*W1+(lx+1+ox);
        m=fmaxf(m, Sl[l1*C+c]+(ox*sx)*wx+(oy*sy)*wy);
      }
    }
    float val=m+c2b[c];
    H2l[e]=val; ls+=val; lq+=val*val;
  }
  __syncthreads();
  sv[t]=ls; sq[t]=lq; __syncthreads();
  for (int o=TT/2;o>=C;o>>=1){ if(t<o){sv[t]+=sv[t+o];sq[t]+=sq[t+o];} __syncthreads(); }
  if (t<C){ atomicAdd(&stH2[t],sv[t]); atomicAdd(&stH2[C+t],sq[t]); }
}

template<int GW,int GH,int TW,int TH,int K,int C,bool POOL>
__device__ __forceinline__ void ph_C(float* buf, float* asv, float* asq, float* la, float* lbv,
    const float* stH2, const float* stSK,
    const float* __restrict__ pw, const float* __restrict__ pb,
    float* __restrict__ outg, float* __restrict__ Gpg, int tile)
{
  constexpr int W2=TW+4, nR2=W2*(TH+4);
  constexpr int W1=TW+2, nR1=W1*(TH+2);
  constexpr int nT=TW*TH, NTX=GW/TW;
  const int tx0=(tile%NTX)*TW, ty0=(tile/NTX)*TH;
  float* Gl=buf; float* Sl=Gl+nR2*K; float* H1l=Sl+nR2*C; float* SKl=H1l+nR1*C; float* H2l=SKl+nT*C;
  const int t=threadIdx.x;
  const float invn=1.f/(float)(GW*GH);
  if (t<C){
    float m2=ldwt(&stH2[t])*invn, v2=ldwt(&stH2[C+t])*invn-m2*m2;
    float i2=rsqrtf(v2+EPSV);
    la[t]=i2; lbv[t]=-m2*i2;
    float ms=ldwt(&stSK[t])*invn, vs=ldwt(&stSK[C+t])*invn-ms*ms;
    float is_=rsqrtf(vs+EPSV);
    asv[t]=is_; asq[t]=-ms*is_;
  }
  __syncthreads();
  float* OUTl=Sl;
  for (int e=t;e<nT*C;e+=TT){
    int cell=e/C,c=e-cell*C;
    int lx=cell%TW, ly=cell/TW;
    int gx=tx0+lx, gy=ty0+ly;
    float v=(H2l[e]*la[c]+lbv[c])+(SKl[e]*asv[c]+asq[c]);
    v=fmaxf(v,0.f);
    outg[(gy*GW+gx)*C+c]=v;
    OUTl[e]=v;
  }
  if constexpr (POOL){
    __syncthreads();
    constexpr int PTW=TW/2, PTH=TH/2, nP=PTW*PTH, PGW=GW/2;
    float* Ml=H1l;
    for (int e=t;e<nP*C;e+=TT){
      int pc=e/C,c=e-pc*C;
      int plx=pc%PTW, ply=pc/PTW;
      float s=0.f;
      #pragma unroll
      for (int dy=0;dy<2;++dy)
        #pragma unroll
        for (int dx=0;dx<2;++dx)
          s += OUTl[((2*ply+dy)*TW+(2*plx+dx))*C+c];
      Ml[e]=s;
    }
    __syncthreads();
    for (int e=t;e<nP*C;e+=TT){
      int pc=e/C,c=e-pc*C;
      int plx=pc%PTW, ply=pc/PTW;
      float acc=pb[c];
      #pragma unroll 8
      for (int k=0;k<C;++k) acc += Ml[pc*C+k]*pw[k*C+c];
      int gpx=tx0/2+plx, gpy=ty0/2+ply;
      stwt(&Gpg[(gpy*PGW+gpx)*C+c], (acc>1.f)?acc:0.f);
    }
  }
  (void)nR1;
}

__global__ void __launch_bounds__(TT) k_tail(TailP P){
  __shared__ float sv[TT], sq[TT], la[128], lbv[128];
  __shared__ float buf[13824];
  int* bar = P.bar;
  const int tile = blockIdx.x;

  // ---- block 2 (80x60, 16->32), tile 4x6, 200 tiles ----
  if (tile < 200) ph_A<80,60,4,6,16,32,true >(buf,sv,sq,P.mem1,P.p1w,P.p1b,P.c1w2,P.c1b2,P.lw2,P.lb2,P.stB2c1,P.stB2sk,3.f,3.f,tile);
  gridbar(bar, 5, NWG);
  if (tile < 200) ph_B<80,60,4,6,16,32>(buf,sv,sq,la,lbv,P.c2w2,P.c2b2,P.stB2c1,P.stB2c2,3.f,3.f,tile);
  gridbar(bar, 6, NWG);
  if (tile < 200) ph_C<80,60,4,6,16,32,true >(buf,sv,sq,la,lbv,P.stB2c2,P.stB2sk,P.p2w,P.p2b,P.out,P.g2p,tile);
  gridbar(bar, 7, NWG);
  // ---- block 3 (40x30, 32->64), tile 2x6, 100 tiles ----
  if (tile < 100) ph_A<40,30,2,6,32,64,false>(buf,sv,sq,P.g2p,nullptr,nullptr,P.c1w3,P.c1b3,P.lw3,P.lb3,P.stB3c1,P.stB3sk,6.f,6.f,tile);
  gridbar(bar, 8, NWG);
  if (tile < 100) ph_B<40,30,2,6,32,64>(buf,sv,sq,la,lbv,P.c2w3,P.c2b3,P.stB3c1,P.stB3c2,6.f,6.f,tile);
  gridbar(bar, 9, NWG);
  if (tile < 100) ph_C<40,30,2,6,32,64,true >(buf,sv,sq,la,lbv,P.stB3c2,P.stB3sk,P.p3w,P.p3b,P.out+153600,P.g3p,tile);
  gridbar(bar, 10, NWG);
  // ---- block 4 (20x15, 64->128), tile 2x3, 50 tiles, no pool ----
  if (tile < 50) ph_A<20,15,2,3,64,128,false>(buf,sv,sq,P.g3p,nullptr,nullptr,P.c1w4,P.c1b4,P.lw4,P.lb4,P.stB4c1,P.stB4sk,12.f,12.f,tile);
  gridbar(bar, 11, NWG);
  if (tile < 50) ph_B<20,15,2,3,64,128>(buf,sv,sq,la,lbv,P.c2w4,P.c2b4,P.stB4c1,P.stB4c2,12.f,12.f,tile);
  gridbar(bar, 12, NWG);
  if (tile < 50) ph_C<20,15,2,3,64,128,false>(buf,sv,sq,la,lbv,P.stB4c2,P.stB4sk,nullptr,nullptr,P.out+230400,nullptr,tile);
}

extern "C" void kernel_launch(void* const* d_in, const int* in_sizes, int n_in,
                              void* d_out, int out_size, void* d_ws, size_t ws_size,
                              hipStream_t stream){
  const float* x   = (const float*)d_in[0];
  const float* pos = (const float*)d_in[1];
  const int*   ei  = (const int*)d_in[2];
  const float* b1_c1w = (const float*)d_in[3];
  const float* b1_c1b = (const float*)d_in[4];
  const float* b1_c2w = (const float*)d_in[5];
  const float* b1_c2b = (const float*)d_in[6];
  const float* b1_lw  = (const float*)d_in[7];
  const float* b2_c1w = (const float*)d_in[9];
  const float* b2_c1b = (const float*)d_in[10];
  const float* b2_c2w = (const float*)d_in[11];
  const float* b2_c2b = (const float*)d_in[12];
  const float* b2_lw  = (const float*)d_in[13];
  const float* b2_lb  = (const float*)d_in[14];
  const float* b3_c1w = (const float*)d_in[15];
  const float* b3_c1b = (const float*)d_in[16];
  const float* b3_c2w = (const float*)d_in[17];
  const float* b3_c2b = (const float*)d_in[18];
  const float* b3_lw  = (const float*)d_in[19];
  const float* b3_lb  = (const float*)d_in[20];
  const float* b4_c1w = (const float*)d_in[21];
  const float* b4_c1b = (const float*)d_in[22];
  const float* b4_c2w = (const float*)d_in[23];
  const float* b4_c2b = (const float*)d_in[24];
  const float* b4_lw  = (const float*)d_in[25];
  const float* b4_lb  = (const float*)d_in[26];
  const float* p1w = (const float*)d_in[27];
  const float* p1b = (const float*)d_in[28];
  const float* p2w = (const float*)d_in[29];
  const float* p2b = (const float*)d_in[30];
  const float* p3w = (const float*)d_in[31];
  const float* p3b = (const float*)d_in[32];
  float* out = (float*)d_out;

  // ---- workspace carve (fp16 A in first half of A region) ----
  float4* feat = (float4*)d_ws;        // NN float4
  float* A  = (float*)(feat + NN);     // NN*16 fp32 region reserved; fp16 A uses NN*8 uints
  float* g2p  = A;                     // 1200*32 — alias, A dead after k_b2f
  float* g3p  = A + 38400;             // 300*64
  // Z region (single memset): sub-bucket counters, barrier flags, stats, mem1
  int* bktCnt  = (int*)(A + NN*16);    // 1024
  int* bktBase = bktCnt + 1024;        // 1025, pad to 1056
  int* bktCur  = bktCnt + 2080;        // 1024; ends 3104, pad to 3200
  int* bar     = bktCnt + 3200;        // flags 200 x stride-32, gen at [6400]; pad to 6464
  float* STz   = (float*)(bktCnt + 3200 + 6464);
  float* xstats = STz;                 // 2
  float* st1p   = STz + 64;            // 16 slots x 32
  float* st2p   = STz + 576;           // 16 slots x 32
  float* stB2sk = STz + 1088;          // 64
  float* stB2c1 = STz + 1152;          // 64
  float* stB2c2 = STz + 1216;          // 64
  float* stB3sk = STz + 1280;          // 128
  float* stB3c1 = STz + 1408;          // 128
  float* stB3c2 = STz + 1536;          // 128
  float* stB4sk = STz + 1664;          // 256
  float* stB4c1 = STz + 1920;          // 256
  float* stB4c2 = STz + 2176;          // ..2431, pad to 2560
  float* mem1   = STz + 2560;          // 76800
  const size_t ZBYTES = (size_t)(3200 + 6464 + 2560 + 76800) * 4;
  int* pairs  = (int*)(mem1 + 76800);  // NE ints

  hipMemsetAsync(bktCnt, 0, ZBYTES, stream);

  // 4 launches + memset
  k_build<<<NBKT, TT, 0, stream>>>(ei, x, pos, feat, xstats, bktCnt, bktBase, bktCur, pairs, bar);
  k_b1f  <<<NBKT, TT, 0, stream>>>(pairs, bktBase, feat, pos,
                                   b1_c1w, b1_c1b, b1_c2w, st1p, (uint2*)A, bar);
  k_b2f  <<<NBKT, TT, 0, stream>>>(pairs, bktBase, (const uint4*)A, feat, pos, x,
                                   b1_c2w+256, b1_c2b, b1_lw, st2p, xstats, mem1, bar);

  TailP P;
  P.mem1 = mem1;
  P.p1w = p1w; P.p1b = p1b; P.p2w = p2w; P.p2b = p2b; P.p3w = p3w; P.p3b = p3b;
  P.c1w2 = b2_c1w; P.c1b2 = b2_c1b; P.c2w2 = b2_c2w; P.c2b2 = b2_c2b; P.lw2 = b2_lw; P.lb2 = b2_lb;
  P.c1w3 = b3_c1w; P.c1b3 = b3_c1b; P.c2w3 = b3_c2w; P.c2b3 = b3_c2b; P.lw3 = b3_lw; P.lb3 = b3_lb;
  P.c1w4 = b4_c1w; P.c1b4 = b4_c1b; P.c2w4 = b4_c2w; P.c2b4 = b4_c2b; P.lw4 = b4_lw; P.lb4 = b4_lb;
  P.g2p = g2p; P.g3p = g3p;
  P.stB2sk = stB2sk; P.stB2c1 = stB2c1; P.stB2c2 = stB2c2;
  P.stB3sk = stB3sk; P.stB3c1 = stB3c1; P.stB3c2 = stB3c2;
  P.stB4sk = stB4sk; P.stB4c1 = stB4c1; P.stB4c2 = stB4c2;
  P.out = out; P.bar = bar;
  k_tail<<<NWG, TT, 0, stream>>>(P);
}

// Round 14
// 377.633 us; speedup vs baseline: 1.0432x; 1.0233x over previous
//
#include <hip/hip_runtime.h>
#include <hip/hip_fp16.h>

#define NN 200000
#define NE 3200000
#define NWG 80          // tail workgroups
#define NBKT 196        // ceil(NN/1024) head workgroups
#define TT 1024
static constexpr float EPSV = 1e-5f;

// ---------------- coherent-point helpers ----------------
__device__ __forceinline__ void stwt(float* p, float v){
  __hip_atomic_store(p, v, __ATOMIC_RELAXED, __HIP_MEMORY_SCOPE_AGENT);
}
__device__ __forceinline__ float ldwt(const float* p){
  return __hip_atomic_load(p, __ATOMIC_RELAXED, __HIP_MEMORY_SCOPE_AGENT);
}
__device__ __forceinline__ void stwt_i(int* p, int v){
  __hip_atomic_store(p, v, __ATOMIC_RELAXED, __HIP_MEMORY_SCOPE_AGENT);
}
__device__ __forceinline__ int ldwt_i(const int* p){
  return __hip_atomic_load(p, __ATOMIC_RELAXED, __HIP_MEMORY_SCOPE_AGENT);
}

// Flag-array barrier, monotonic targets shared across the launch sequence.
// flags at bar[32*wg] (wg in [0,196)); generation at bar[6272].
__device__ __forceinline__ void gridbar(int* bar, int target, int nwg){
  __syncthreads();   // compiler drains each wave's vm/lgkm before s_barrier
  const int t = threadIdx.x;
  if (blockIdx.x == 0){
    if (t >= 1 && t < nwg){
      while (__hip_atomic_load(bar + 32*t, __ATOMIC_RELAXED, __HIP_MEMORY_SCOPE_AGENT) < target)
        __builtin_amdgcn_s_sleep(1);
    }
    __syncthreads();
    if (t == 0)
      __hip_atomic_store(bar + 6272, target, __ATOMIC_RELAXED, __HIP_MEMORY_SCOPE_AGENT);
  } else {
    if (t == 0){
      __atomic_signal_fence(__ATOMIC_SEQ_CST);
      __builtin_amdgcn_s_waitcnt(0);   // this wave's stores durable before arrival flag
      __atomic_signal_fence(__ATOMIC_SEQ_CST);
      __hip_atomic_store(bar + 32*blockIdx.x, target, __ATOMIC_RELAXED, __HIP_MEMORY_SCOPE_AGENT);
      while (__hip_atomic_load(bar + 6272, __ATOMIC_RELAXED, __HIP_MEMORY_SCOPE_AGENT) < target)
        __builtin_amdgcn_s_sleep(2);
    }
    __syncthreads();
  }
}

// ---------------- fused CSR build: register-cached edges, single ei read ----------------
// 1024 sub-buckets: key = (dst>>10)<<2 | (src>>16). Within each dst bucket the pairs
// end up src-sorted by 64K window -> agg gathers sweep A/feat in ~2MB L2-resident phases.
// Each thread caches its 16 (d,s) edges in registers; per-WG bucket slots reserved via
// one global atomicAdd before the barrier; scatter runs from registers (no ei re-read).
__global__ void __launch_bounds__(1024) k_build(const int* __restrict__ ei,
    const float* __restrict__ x, const float* __restrict__ pos,
    float4* __restrict__ feat, float* __restrict__ xstats,
    int* __restrict__ bktCur, int* __restrict__ bktBase,
    int* __restrict__ pairs, int* __restrict__ bar){
  __shared__ int cnt[1024]; __shared__ int resv[1024];
  __shared__ float sv[1024], sq[1024];
  const int t = threadIdx.x, wg = blockIdx.x;
  const int tile = wg*16384;
  int ed[16], es[16];
  // phase 0: feat prep + xstats + local count (edges cached to registers)
  cnt[t] = 0;
  int i = wg*1024 + t;
  float xf = 0.f;
  if (i < NN){
    xf = x[i];
    feat[i] = make_float4(xf, pos[3*i], pos[3*i+1], 0.f);
  }
  sv[t] = (i < NN) ? xf : 0.f;
  sq[t] = sv[t]*sv[t];
  __syncthreads();
  #pragma unroll
  for (int k = 0; k < 16; ++k){
    int e = tile + k*1024 + t;
    if (e < NE){
      ed[k] = ei[NE+e]; es[k] = ei[e];
      atomicAdd(&cnt[((ed[k]>>10)<<2) | (es[k]>>16)], 1);
    } else ed[k] = -1;
  }
  for (int o = 512; o > 0; o >>= 1){
    __syncthreads();
    if (t < o){ sv[t]+=sv[t+o]; sq[t]+=sq[t+o]; }
  }
  __syncthreads();
  if (t == 0){ atomicAdd(&xstats[0], sv[0]); atomicAdd(&xstats[1], sq[0]); }
  // reserve this WG's slot in each bucket (global atomics = coherent)
  resv[t] = cnt[t] ? atomicAdd(&bktCur[t], cnt[t]) : 0;
  gridbar(bar, 1, NBKT);
  // phase 1: wg0 exclusive scan of bucket totals (write-through: intra-kernel consumers)
  if (wg == 0){
    int v = ldwt_i(&bktCur[t]);
    cnt[t] = v;   // wg0's local counts no longer needed (resv holds its reservation)
    __syncthreads();
    for (int o = 1; o < 1024; o <<= 1){
      int xv = (t >= o) ? cnt[t-o] : 0;
      __syncthreads();
      cnt[t] += xv;
      __syncthreads();
    }
    stwt_i(&bktBase[t], cnt[t]-v);
    if (t == 0) stwt_i(&bktBase[1024], NE);
  }
  gridbar(bar, 2, NBKT);
  // phase 2: scatter from registers (CACHED pairs stores; consumers are later kernels)
  int* rank = (int*)sv;
  int* bb   = (int*)sq;
  rank[t] = 0;
  bb[t] = ldwt_i(&bktBase[t]);
  __syncthreads();
  #pragma unroll
  for (int k = 0; k < 16; ++k){
    if (ed[k] >= 0){
      int b = ((ed[k]>>10)<<2) | (es[k]>>16);
      int r = atomicAdd(&rank[b], 1);
      pairs[bb[b] + resv[b] + r] = (es[k]<<10) | (ed[k] & 1023);
    }
  }
}

// ---------------- order-preserving float<->uint for atomicMax ----------------
__device__ __forceinline__ unsigned fenc(float f){
  unsigned u = __float_as_uint(f);
  return (u >> 31) ? ~u : (u | 0x80000000u);
}
__device__ __forceinline__ float fdec(unsigned k){
  unsigned u = (k >> 31) ? (k ^ 0x80000000u) : ~k;
  return __uint_as_float(u);
}
#define ENC_NI 0x007FFFFFu   /* fenc(-inf) */

// ---------------- fused: aggA (LDS-resident H1) + stats + prep2 (fp16 A, no pos bake) ----------------
__global__ void __launch_bounds__(1024) k_b1f(const int* __restrict__ pairs, const int* __restrict__ bktBase,
    const float4* __restrict__ feat, const float* __restrict__ pos,
    const float* __restrict__ w48, const float* __restrict__ biasA,
    const float* __restrict__ w2, float* __restrict__ st1p, uint2* __restrict__ A2,
    int* __restrict__ bar){
  __shared__ unsigned acc[16384];   // 1024 dst x 16 ch (swizzled), 64KB
  const int t = threadIdx.x, wg = blockIdx.x;
  for (int i = t; i < 16384; i += 1024) acc[i] = ENC_NI;
  float wa0[16], wa1[16], wa2[16];
  #pragma unroll
  for (int c = 0; c < 16; ++c){ wa0[c]=w48[c]; wa1[c]=w48[16+c]; wa2[c]=w48[32+c]; }
  const int p0 = bktBase[wg*4], p1 = bktBase[wg*4+4];
  __syncthreads();
  for (int j = p0 + t; j < p1; j += 1024){
    int pr = pairs[j];
    float4 f = feat[pr >> 10];
    int d = pr & 1023;
    int gb = d << 4, rot = (d >> 1) & 15;
    #pragma unroll
    for (int c = 0; c < 16; ++c){
      float m = f.x*wa0[c] + f.y*wa1[c] + f.z*wa2[c];
      atomicMax(&acc[gb | ((c + rot) & 15)], fenc(m));
    }
  }
  __syncthreads();
  const int base = wg << 10;
  const int width = min(1024, NN - base);
  // H1 stats only (H1 never leaves LDS)
  {
    const int c = t & 15;
    const float b_c = biasA[c], w1c = w48[16+c], w2c = w48[32+c];
    float ls = 0.f, lq = 0.f;
    for (int i = t; i < width*16; i += 1024){
      int dl = i >> 4, d = base + dl;
      int rot = (dl >> 1) & 15;
      float o = 0.f;
      if (acc[(dl<<4) | rot] != ENC_NI){
        float px = pos[3*d], py = pos[3*d+1];
        o = fdec(acc[(dl<<4) | ((c + rot) & 15)]) + b_c - (px*w1c + py*w2c);
      }
      ls += o; lq += o*o;
    }
    ls += __shfl_xor(ls, 16, 64); ls += __shfl_xor(ls, 32, 64);
    lq += __shfl_xor(lq, 16, 64); lq += __shfl_xor(lq, 32, 64);
    if ((t & 63) < 16){
      int slot = (wg + (t >> 6)) & 15;
      atomicAdd(&st1p[slot*32 + c], ls);
      atomicAdd(&st1p[slot*32 + 16 + c], lq);
    }
  }
  gridbar(bar, 3, NBKT);
  // prep2 from LDS acc -> A2 (fp16, WITHOUT src-pos terms; added exactly in b2f)
  {
    const int lane = t & 63;
    float stv = 0.f;
    if (lane < 32){
      #pragma unroll
      for (int s2 = 0; s2 < 16; ++s2) stv += ldwt(&st1p[s2*32 + lane]);
    }
    const float inv_n = 1.f/(float)NN;
    float mk[16], ik[16];
    #pragma unroll
    for (int k = 0; k < 16; ++k){
      float sm = __shfl(stv, k, 64);
      float sq_ = __shfl(stv, 16 + k, 64);
      float m = sm*inv_n;
      float v = sq_*inv_n - m*m;
      mk[k] = m; ik[k] = rsqrtf(v + EPSV);
    }
    for (int i = t; i < width*4; i += 1024){
      int dl = i >> 2, cg = i & 3, d = base + dl;
      int rot = (dl >> 1) & 15;
      bool valid = (acc[(dl<<4) | rot] != ENC_NI);
      float px = pos[3*d], py = pos[3*d+1];
      float a0=0.f,a1=0.f,a2=0.f,a3=0.f;
      #pragma unroll
      for (int k = 0; k < 16; ++k){
        float o = 0.f;
        if (valid) o = fdec(acc[(dl<<4) | ((k + rot) & 15)]) + biasA[k] - (px*w48[16+k] + py*w48[32+k]);
        float h = fmaxf((o - mk[k])*ik[k], 0.f);
        a0 += h*w2[k*16 + cg*4 + 0];
        a1 += h*w2[k*16 + cg*4 + 1];
        a2 += h*w2[k*16 + cg*4 + 2];
        a3 += h*w2[k*16 + cg*4 + 3];
      }
      __half2 h01 = __floats2half2_rn(a0, a1);
      __half2 h23 = __floats2half2_rn(a2, a3);
      uint2 pk;
      pk.x = *reinterpret_cast<unsigned*>(&h01);
      pk.y = *reinterpret_cast<unsigned*>(&h23);
      A2[d*4 + cg] = pk;
    }
  }
}

// ---------------- fused: aggB (fp16 A gather + exact fp32 src-pos) + stats + comb_pool ----------------
__global__ void __launch_bounds__(1024) k_b2f(const int* __restrict__ pairs, const int* __restrict__ bktBase,
    const uint4* __restrict__ Ah, const float4* __restrict__ feat,
    const float* __restrict__ pos, const float* __restrict__ x,
    const float* __restrict__ wpos, const float* __restrict__ biasB, const float* __restrict__ lw,
    float* __restrict__ st2p, const float* __restrict__ xstats,
    float* __restrict__ mem1, int* __restrict__ bar){
  __shared__ unsigned acc[16384];
  const int t = threadIdx.x, wg = blockIdx.x;
  for (int i = t; i < 16384; i += 1024) acc[i] = ENC_NI;
  float wx[16], wy[16];
  #pragma unroll
  for (int c = 0; c < 16; ++c){ wx[c]=wpos[c]; wy[c]=wpos[16+c]; }
  const int p0 = bktBase[wg*4], p1 = bktBase[wg*4+4];
  __syncthreads();
  for (int j = p0 + t; j < p1; j += 1024){
    int pr = pairs[j];
    int s = pr >> 10, d = pr & 1023;
    int gb = d << 4, rot = (d >> 1) & 15;
    float4 f = feat[s];             // src-window-ordered -> L2-resident phase
    uint4 q0 = Ah[s*2+0], q1 = Ah[s*2+1];   // 32B fp16 A row, same ordering
    float m[16];
    {
      float2 u;
      u = __half22float2(*reinterpret_cast<__half2*>(&q0.x)); m[0]=u.x;  m[1]=u.y;
      u = __half22float2(*reinterpret_cast<__half2*>(&q0.y)); m[2]=u.x;  m[3]=u.y;
      u = __half22float2(*reinterpret_cast<__half2*>(&q0.z)); m[4]=u.x;  m[5]=u.y;
      u = __half22float2(*reinterpret_cast<__half2*>(&q0.w)); m[6]=u.x;  m[7]=u.y;
      u = __half22float2(*reinterpret_cast<__half2*>(&q1.x)); m[8]=u.x;  m[9]=u.y;
      u = __half22float2(*reinterpret_cast<__half2*>(&q1.y)); m[10]=u.x; m[11]=u.y;
      u = __half22float2(*reinterpret_cast<__half2*>(&q1.z)); m[12]=u.x; m[13]=u.y;
      u = __half22float2(*reinterpret_cast<__half2*>(&q1.w)); m[14]=u.x; m[15]=u.y;
    }
    #pragma unroll
    for (int c = 0; c < 16; ++c){
      float mv = m[c] + f.y*wx[c] + f.z*wy[c];
      atomicMax(&acc[gb | ((c + rot) & 15)], fenc(mv));
    }
  }
  __syncthreads();
  const int base = wg << 10;
  const int width = min(1024, NN - base);
  const int c = t & 15;
  const float b_c = biasB[c], w1c = wpos[c], w2c = wpos[16+c];
  // H2 stats only (H2 never leaves LDS)
  {
    float ls = 0.f, lq = 0.f;
    for (int i = t; i < width*16; i += 1024){
      int dl = i >> 4, d = base + dl;
      int rot = (dl >> 1) & 15;
      float o = 0.f;
      if (acc[(dl<<4) | rot] != ENC_NI){
        float px = pos[3*d], py = pos[3*d+1];
        o = fdec(acc[(dl<<4) | ((c + rot) & 15)]) + b_c - (px*w1c + py*w2c);
      }
      ls += o; lq += o*o;
    }
    ls += __shfl_xor(ls, 16, 64); ls += __shfl_xor(ls, 32, 64);
    lq += __shfl_xor(lq, 16, 64); lq += __shfl_xor(lq, 32, 64);
    if ((t & 63) < 16){
      int slot = (wg + (t >> 6)) & 15;
      atomicAdd(&st2p[slot*32 + c], ls);
      atomicAdd(&st2p[slot*32 + 16 + c], lq);
    }
  }
  gridbar(bar, 4, NBKT);
  // comb + pool into mem1 (from LDS acc)
  {
    const int lane = t & 63;
    float stv = 0.f;
    if (lane < 32){
      #pragma unroll
      for (int s2 = 0; s2 < 16; ++s2) stv += ldwt(&st2p[s2*32 + lane]);
    }
    const float inv_n = 1.f/(float)NN;
    float sm = __shfl(stv, c, 64), sq_ = __shfl(stv, 16 + c, 64);
    float m2 = sm*inv_n, v2 = sq_*inv_n - m2*m2;
    float i2 = rsqrtf(v2 + EPSV);
    float mx = ldwt(&xstats[0])*inv_n;
    float vx = ldwt(&xstats[1])*inv_n - mx*mx;
    float a = lw[c];
    float sc = a * rsqrtf(a*a*vx + EPSV);
    for (int i = t; i < width*16; i += 1024){
      int dl = i >> 4, d = base + dl;
      int rot = (dl >> 1) & 15;
      float px = pos[3*d], py = pos[3*d+1];
      float o = 0.f;
      if (acc[(dl<<4) | rot] != ENC_NI)
        o = fdec(acc[(dl<<4) | ((c + rot) & 15)]) + b_c - (px*w1c + py*w2c);
      float v = (o - m2)*i2 + (x[d]-mx)*sc;
      v = fmaxf(v, 0.f);
      int cx = (int)(px * 80.f / 240.f); cx = min(max(cx,0),79);
      int cy = (int)(py * 60.f / 180.f); cy = min(max(cy,0),59);
      atomicAdd(&mem1[(cy*80+cx)*16 + c], v);
    }
  }
}

// ---------------- Fused tail: halo-tiled, LDS-resident (r11 geometry, 80 WGs) ----------------
struct TailP {
  const float *mem1;
  const float *p1w,*p1b,*p2w,*p2b,*p3w,*p3b;
  const float *c1w2,*c1b2,*c2w2,*c2b2,*lw2,*lb2;
  const float *c1w3,*c1b3,*c2w3,*c2b3,*lw3,*lb3;
  const float *c1w4,*c1b4,*c2w4,*c2b4,*lw4,*lb4;
  float *g2p,*g3p;
  float *stB2sk,*stB2c1,*stB2c2,*stB3sk,*stB3c1,*stB3c2,*stB4sk,*stB4c1,*stB4c2;
  float *out;
  int *bar;
};

template<int GW,int GH,int TW,int TH,int K,int C,bool FIRST>
__device__ __forceinline__ void ph_A(float* buf, float* sv, float* sq,
    const float* __restrict__ Gglob, const float* __restrict__ plw, const float* __restrict__ plb,
    const float* __restrict__ c1w, const float* __restrict__ c1b,
    const float* __restrict__ lw, const float* __restrict__ lb,
    float* stH1, float* stSK, float sx, float sy, int tile)
{
  constexpr int W2=TW+4, nR2=W2*(TH+4);
  constexpr int W1=TW+2, nR1=W1*(TH+2);
  constexpr int nT=TW*TH, NTX=GW/TW;
  const int tx0=(tile%NTX)*TW, ty0=(tile/NTX)*TH;
  float* Gl=buf; float* Sl=Gl+nR2*K; float* H1l=Sl+nR2*C; float* SKl=H1l+nR1*C;
  const int t=threadIdx.x;
  if constexpr (FIRST){
    for (int e=t; e<nR2*K; e+=TT){
      int cell=e/K, k=e-cell*K;
      int gx=tx0-2+cell%W2, gy=ty0-2+cell/W2;
      Sl[e] = (gx>=0&&gx<GW&&gy>=0&&gy<GH) ? Gglob[(gy*GW+gx)*K+k] : 0.f;
    }
    __syncthreads();
    for (int e=t; e<nR2*K; e+=TT){
      int cell=e/K, c=e-cell*K;
      float acc=plb[c];
      #pragma unroll
      for (int k=0;k<K;++k) acc += Sl[cell*K+k]*plw[k*K+c];
      Gl[e] = (acc>1.f)?acc:0.f;
    }
  } else {
    for (int e=t; e<nR2*K; e+=TT){
      int cell=e/K, k=e-cell*K;
      int gx=tx0-2+cell%W2, gy=ty0-2+cell/W2;
      Gl[e] = (gx>=0&&gx<GW&&gy>=0&&gy<GH) ? ldwt(&Gglob[(gy*GW+gx)*K+k]) : 0.f;
    }
  }
  __syncthreads();
  for (int e=t; e<nR2*C; e+=TT){
    int cell=e/C, c=e-cell*C;
    float acc=0.f;
    #pragma unroll 8
    for (int k=0;k<K;++k) acc += Gl[cell*K+k]*c1w[k*C+c];
    Sl[e]=acc;
  }
  float ls=0.f,lq=0.f;
  for (int e=t; e<nT*C; e+=TT){
    int cell=e/C, c=e-cell*C;
    int lx=cell%TW, ly=cell/TW;
    int g2=(ly+2)*W2+(lx+2);
    float acc=lb[c];
    #pragma unroll 8
    for (int k=0;k<K;++k) acc += Gl[g2*K+k]*lw[k*C+c];
    SKl[e]=acc; ls+=acc; lq+=acc*acc;
  }
  __syncthreads();
  sv[t]=ls; sq[t]=lq; __syncthreads();
  for (int o=TT/2;o>=C;o>>=1){ if(t<o){sv[t]+=sv[t+o];sq[t]+=sq[t+o];} __syncthreads(); }
  if (t<C){ atomicAdd(&stSK[t],sv[t]); atomicAdd(&stSK[C+t],sq[t]); }
  __syncthreads();
  ls=0.f; lq=0.f;
  const float NI=-__builtin_inff();
  for (int e=t; e<nR1*C; e+=TT){
    int cell=e/C, c=e-cell*C;
    int lx=cell%W1, ly=cell/W1;
    int gx=tx0-1+lx, gy=ty0-1+ly;
    if (gx<0||gx>=GW||gy<0||gy>=GH) continue;
    float wx=c1w[K*C+c], wy=c1w[(K+1)*C+c];
    float m=NI;
    #pragma unroll
    for (int oy=-1;oy<=1;++oy){
      int ny=gy+oy; if (ny<0||ny>=GH) continue;
      #pragma unroll
      for (int ox=-1;ox<=1;++ox){
        int nx=gx+ox; if (nx<0||nx>=GW) continue;
        int l2=(ly+1+oy)*W2+(lx+1+ox);
        m=fmaxf(m, Sl[l2*C+c]+(ox*sx)*wx+(oy*sy)*wy);
      }
    }
    float val=m+c1b[c];
    H1l[e]=val;
    if (gx>=tx0&&gx<tx0+TW&&gy>=ty0&&gy<ty0+TH){ ls+=val; lq+=val*val; }
  }
  __syncthreads();
  sv[t]=ls; sq[t]=lq; __syncthreads();
  for (int o=TT/2;o>=C;o>>=1){ if(t<o){sv[t]+=sv[t+o];sq[t]+=sq[t+o];} __syncthreads(); }
  if (t<C){ atomicAdd(&stH1[t],sv[t]); atomicAdd(&stH1[C+t],sq[t]); }
}

template<int GW,int GH,int TW,int TH,int K,int C>
__device__ __forceinline__ void ph_B(float* buf, float* sv, float* sq, float* la, float* lbv,
    const float* __restrict__ c2w, const float* __restrict__ c2b,
    const float* stH1, float* stH2, float sx, float sy, int tile)
{
  constexpr int W2=TW+4, nR2=W2*(TH+4);
  constexpr int W1=TW+2, nR1=W1*(TH+2);
  constexpr int nT=TW*TH, NTX=GW/TW;
  const int tx0=(tile%NTX)*TW, ty0=(tile/NTX)*TH;
  float* Gl=buf; float* Sl=Gl+nR2*K; float* H1l=Sl+nR2*C; float* SKl=H1l+nR1*C; float* H2l=SKl+nT*C;
  const int t=threadIdx.x;
  const float invn=1.f/(float)(GW*GH);
  if (t<C){
    float mk=ldwt(&stH1[t])*invn;
    float vk=ldwt(&stH1[C+t])*invn - mk*mk;
    float ik=rsqrtf(vk+EPSV);
    la[t]=ik; lbv[t]=-mk*ik;
  }
  __syncthreads();
  for (int e=t;e<nR1*C;e+=TT){
    int cell=e/C,c=e-cell*C;
    int gx=tx0-1+cell%W1, gy=ty0-1+cell/W1;
    if (gx<0||gx>=GW||gy<0||gy>=GH) continue;
    H1l[e]=fmaxf(H1l[e]*la[c]+lbv[c],0.f);
  }
  __syncthreads();
  for (int e=t;e<nR1*C;e+=TT){
    int cell=e/C,c=e-cell*C;
    int gx=tx0-1+cell%W1, gy=ty0-1+cell/W1;
    if (gx<0||gx>=GW||gy<0||gy>=GH) continue;
    float acc=0.f;
    #pragma unroll 8
    for (int k=0;k<C;++k) acc += H1l[cell*C+k]*c2w[k*C+c];
    Sl[e]=acc;
  }
  __syncthreads();
  float ls=0.f,lq=0.f;
  const float NI=-__builtin_inff();
  for (int e=t;e<nT*C;e+=TT){
    int cell=e/C,c=e-cell*C;
    int lx=cell%TW, ly=cell/TW;
    int gx=tx0+lx, gy=ty0+ly;
    float wx=c2w[C*C+c], wy=c2w[(C+1)*C+c];
    float m=NI;
    #pragma unroll
    for (int oy=-1;oy<=1;++oy){
      int ny=gy+oy; if (ny<0||ny>=GH) continue;
      #pragma unroll
      for (int ox=-1;ox<=1;++ox){
        int nx=gx+ox; if (nx<0||nx>=GW) continue;
        int l1=(ly+1+oy)*W1+(lx+1+ox);
        m=fmaxf(m, Sl[l1*C+c]+(ox*sx)*wx+(oy*sy)*wy);
      }
    }
    float val=m+c2b[c];
    H2l[e]=val; ls+=val; lq+=val*val;
  }
  __syncthreads();
  sv[t]=ls; sq[t]=lq; __syncthreads();
  for (int o=TT/2;o>=C;o>>=1){ if(t<o){sv[t]+=sv[t+o];sq[t]+=sq[t+o];} __syncthreads(); }
  if (t<C){ atomicAdd(&stH2[t],sv[t]); atomicAdd(&stH2[C+t],sq[t]); }
}

template<int GW,int GH,int TW,int TH,int K,int C,bool POOL>
__device__ __forceinline__ void ph_C(float* buf, float* asv, float* asq, float* la, float* lbv,
    const float* stH2, const float* stSK,
    const float* __restrict__ pw, const float* __restrict__ pb,
    float* __restrict__ outg, float* __restrict__ Gpg, int tile)
{
  constexpr int W2=TW+4, nR2=W2*(TH+4);
  constexpr int W1=TW+2, nR1=W1*(TH+2);
  constexpr int nT=TW*TH, NTX=GW/TW;
  const int tx0=(tile%NTX)*TW, ty0=(tile/NTX)*TH;
  float* Gl=buf; float* Sl=Gl+nR2*K; float* H1l=Sl+nR2*C; float* SKl=H1l+nR1*C; float* H2l=SKl+nT*C;
  const int t=threadIdx.x;
  const float invn=1.f/(float)(GW*GH);
  if (t<C){
    float m2=ldwt(&stH2[t])*invn, v2=ldwt(&stH2[C+t])*invn-m2*m2;
    float i2=rsqrtf(v2+EPSV);
    la[t]=i2; lbv[t]=-m2*i2;
    float ms=ldwt(&stSK[t])*invn, vs=ldwt(&stSK[C+t])*invn-ms*ms;
    float is_=rsqrtf(vs+EPSV);
    asv[t]=is_; asq[t]=-ms*is_;
  }
  __syncthreads();
  float* OUTl=Sl;
  for (int e=t;e<nT*C;e+=TT){
    int cell=e/C,c=e-cell*C;
    int lx=cell%TW, ly=cell/TW;
    int gx=tx0+lx, gy=ty0+ly;
    float v=(H2l[e]*la[c]+lbv[c])+(SKl[e]*asv[c]+asq[c]);
    v=fmaxf(v,0.f);
    outg[(gy*GW+gx)*C+c]=v;
    OUTl[e]=v;
  }
  if constexpr (POOL){
    __syncthreads();
    constexpr int PTW=TW/2, PTH=TH/2, nP=PTW*PTH, PGW=GW/2;
    float* Ml=H1l;
    for (int e=t;e<nP*C;e+=TT){
      int pc=e/C,c=e-pc*C;
      int plx=pc%PTW, ply=pc/PTW;
      float s=0.f;
      #pragma unroll
      for (int dy=0;dy<2;++dy)
        #pragma unroll
        for (int dx=0;dx<2;++dx)
          s += OUTl[((2*ply+dy)*TW+(2*plx+dx))*C+c];
      Ml[e]=s;
    }
    __syncthreads();
    for (int e=t;e<nP*C;e+=TT){
      int pc=e/C,c=e-pc*C;
      int plx=pc%PTW, ply=pc/PTW;
      float acc=pb[c];
      #pragma unroll 8
      for (int k=0;k<C;++k) acc += Ml[pc*C+k]*pw[k*C+c];
      int gpx=tx0/2+plx, gpy=ty0/2+ply;
      stwt(&Gpg[(gpy*PGW+gpx)*C+c], (acc>1.f)?acc:0.f);
    }
  }
  (void)nR1;
}

__global__ void __launch_bounds__(TT) k_tail(TailP P){
  __shared__ float sv[TT], sq[TT], la[128], lbv[128];
  __shared__ float buf[13824];
  int* bar = P.bar;
  const int tile = blockIdx.x;

  if (tile < 80) ph_A<80,60,10,6,16,32,true >(buf,sv,sq,P.mem1,P.p1w,P.p1b,P.c1w2,P.c1b2,P.lw2,P.lb2,P.stB2c1,P.stB2sk,3.f,3.f,tile);
  gridbar(bar, 5, NWG);
  if (tile < 80) ph_B<80,60,10,6,16,32>(buf,sv,sq,la,lbv,P.c2w2,P.c2b2,P.stB2c1,P.stB2c2,3.f,3.f,tile);
  gridbar(bar, 6, NWG);
  if (tile < 80) ph_C<80,60,10,6,16,32,true >(buf,sv,sq,la,lbv,P.stB2c2,P.stB2sk,P.p2w,P.p2b,P.out,P.g2p,tile);
  gridbar(bar, 7, NWG);
  if (tile < 50) ph_A<40,30,4,6,32,64,false>(buf,sv,sq,P.g2p,nullptr,nullptr,P.c1w3,P.c1b3,P.lw3,P.lb3,P.stB3c1,P.stB3sk,6.f,6.f,tile);
  gridbar(bar, 8, NWG);
  if (tile < 50) ph_B<40,30,4,6,32,64>(buf,sv,sq,la,lbv,P.c2w3,P.c2b3,P.stB3c1,P.stB3c2,6.f,6.f,tile);
  gridbar(bar, 9, NWG);
  if (tile < 50) ph_C<40,30,4,6,32,64,true >(buf,sv,sq,la,lbv,P.stB3c2,P.stB3sk,P.p3w,P.p3b,P.out+153600,P.g3p,tile);
  gridbar(bar, 10, NWG);
  if (tile < 50) ph_A<20,15,2,3,64,128,false>(buf,sv,sq,P.g3p,nullptr,nullptr,P.c1w4,P.c1b4,P.lw4,P.lb4,P.stB4c1,P.stB4sk,12.f,12.f,tile);
  gridbar(bar, 11, NWG);
  if (tile < 50) ph_B<20,15,2,3,64,128>(buf,sv,sq,la,lbv,P.c2w4,P.c2b4,P.stB4c1,P.stB4c2,12.f,12.f,tile);
  gridbar(bar, 12, NWG);
  if (tile < 50) ph_C<20,15,2,3,64,128,false>(buf,sv,sq,la,lbv,P.stB4c2,P.stB4sk,nullptr,nullptr,P.out+230400,nullptr,tile);
}

extern "C" void kernel_launch(void* const* d_in, const int* in_sizes, int n_in,
                              void* d_out, int out_size, void* d_ws, size_t ws_size,
                              hipStream_t stream){
  const float* x   = (const float*)d_in[0];
  const float* pos = (const float*)d_in[1];
  const int*   ei  = (const int*)d_in[2];
  const float* b1_c1w = (const float*)d_in[3];
  const float* b1_c1b = (const float*)d_in[4];
  const float* b1_c2w = (const float*)d_in[5];
  const float* b1_c2b = (const float*)d_in[6];
  const float* b1_lw  = (const float*)d_in[7];
  const float* b2_c1w = (const float*)d_in[9];
  const float* b2_c1b = (const float*)d_in[10];
  const float* b2_c2w = (const float*)d_in[11];
  const float* b2_c2b = (const float*)d_in[12];
  const float* b2_lw  = (const float*)d_in[13];
  const float* b2_lb  = (const float*)d_in[14];
  const float* b3_c1w = (const float*)d_in[15];
  const float* b3_c1b = (const float*)d_in[16];
  const float* b3_c2w = (const float*)d_in[17];
  const float* b3_c2b = (const float*)d_in[18];
  const float* b3_lw  = (const float*)d_in[19];
  const float* b3_lb  = (const float*)d_in[20];
  const float* b4_c1w = (const float*)d_in[21];
  const float* b4_c1b = (const float*)d_in[22];
  const float* b4_c2w = (const float*)d_in[23];
  const float* b4_c2b = (const float*)d_in[24];
  const float* b4_lw  = (const float*)d_in[25];
  const float* b4_lb  = (const float*)d_in[26];
  const float* p1w = (const float*)d_in[27];
  const float* p1b = (const float*)d_in[28];
  const float* p2w = (const float*)d_in[29];
  const float* p2b = (const float*)d_in[30];
  const float* p3w = (const float*)d_in[31];
  const float* p3b = (const float*)d_in[32];
  float* out = (float*)d_out;

  // ---- workspace carve (fp16 A in first half of A region) ----
  float4* feat = (float4*)d_ws;        // NN float4
  float* A  = (float*)(feat + NN);     // NN*16 fp32 region reserved; fp16 A uses NN*8 uints
  float* g2p  = A;                     // 1200*32 — alias, A dead after k_b2f
  float* g3p  = A + 38400;             // 300*64
  // Z region (single memset): sub-bucket counters, barrier flags, stats, mem1
  int* bktCur  = (int*)(A + NN*16);    // 1024 (bucket totals via reservation)
  int* bktBase = bktCur + 1024;        // 1025, pad region to 3200 total
  int* bar     = bktCur + 3200;        // flags 196 x stride-32, gen at [6272]; pad to 6400
  float* STz   = (float*)(bktCur + 3200 + 6400);
  float* xstats = STz;                 // 2
  float* st1p   = STz + 64;            // 16 slots x 32
  float* st2p   = STz + 576;           // 16 slots x 32
  float* stB2sk = STz + 1088;          // 64
  float* stB2c1 = STz + 1152;          // 64
  float* stB2c2 = STz + 1216;          // 64
  float* stB3sk = STz + 1280;          // 128
  float* stB3c1 = STz + 1408;          // 128
  float* stB3c2 = STz + 1536;          // 128
  float* stB4sk = STz + 1664;          // 256
  float* stB4c1 = STz + 1920;          // 256
  float* stB4c2 = STz + 2176;          // ..2431, pad to 2560
  float* mem1   = STz + 2560;          // 76800
  const size_t ZBYTES = (size_t)(3200 + 6400 + 2560 + 76800) * 4;
  int* pairs  = (int*)(mem1 + 76800);  // NE ints

  hipMemsetAsync(bktCur, 0, ZBYTES, stream);

  // 4 launches + memset
  k_build<<<NBKT, TT, 0, stream>>>(ei, x, pos, feat, xstats, bktCur, bktBase, pairs, bar);
  k_b1f  <<<NBKT, TT, 0, stream>>>(pairs, bktBase, feat, pos,
                                   b1_c1w, b1_c1b, b1_c2w, st1p, (uint2*)A, bar);
  k_b2f  <<<NBKT, TT, 0, stream>>>(pairs, bktBase, (const uint4*)A, feat, pos, x,
                                   b1_c2w+256, b1_c2b, b1_lw, st2p, xstats, mem1, bar);

  TailP P;
  P.mem1 = mem1;
  P.p1w = p1w; P.p1b = p1b; P.p2w = p2w; P.p2b = p2b; P.p3w = p3w; P.p3b = p3b;
  P.c1w2 = b2_c1w; P.c1b2 = b2_c1b; P.c2w2 = b2_c2w; P.c2b2 = b2_c2b; P.lw2 = b2_lw; P.lb2 = b2_lb;
  P.c1w3 = b3_c1w; P.c1b3 = b3_c1b; P.c2w3 = b3_c2w; P.c2b3 = b3_c2b; P.lw3 = b3_lw; P.lb3 = b3_lb;
  P.c1w4 = b4_c1w; P.c1b4 = b4_c1b; P.c2w4 = b4_c2w; P.c2b4 = b4_c2b; P.lw4 = b4_lw; P.lb4 = b4_lb;
  P.g2p = g2p; P.g3p = g3p;
  P.stB2sk = stB2sk; P.stB2c1 = stB2c1; P.stB2c2 = stB2c2;
  P.stB3sk = stB3sk; P.stB3c1 = stB3c1; P.stB3c2 = stB3c2;
  P.stB4sk = stB4sk; P.stB4c1 = stB4c1; P.stB4c2 = stB4c2;
  P.out = out; P.bar = bar;
  k_tail<<<NWG, TT, 0, stream>>>(P);
}